// Round 4
// baseline (4583.635 us; speedup 1.0000x reference)
//
#include <hip/hip_runtime.h>
#include <math.h>

#define NB 32
#define NS 400
#define NM 400
#define NH 200
#define NP 16
#define NT 4
#define NBS (NB*NS)          // 12800
#define NPH (NP*NH)          // 3200
#define NX  (2*NM)           // 800
#define NG  (4*NH)           // 800
#define NR  (2*NM+NH)        // 1000
#define K1  1280             // m1 GEMM K' (3*400 padded to /32)
#define K2  640              // m2 GEMM K' (3*200 padded to /32)

typedef __attribute__((ext_vector_type(8))) short short8v;
typedef __attribute__((ext_vector_type(4))) float f32x4;
typedef __attribute__((ext_vector_type(4))) unsigned short us4;
typedef unsigned short ushort;

__device__ __forceinline__ float sigf(float x){ return 1.0f/(1.0f+expf(-x)); }

__device__ __forceinline__ ushort f2bf(float x){
  union{float f; unsigned u;} v; v.f=x;
  unsigned r = v.u + 0x7fffu + ((v.u>>16)&1u);
  return (ushort)(r>>16);
}
__device__ __forceinline__ float bf2f(ushort u){
  union{float f; unsigned v;} x; x.v = ((unsigned)u)<<16; return x.f;
}
__device__ __forceinline__ float wave_sum(float v){
  #pragma unroll
  for (int o=32;o>0;o>>=1) v += __shfl_xor(v, o);
  return v;
}

// ---------------- init: h=c=0, sprev=0, eprev=sum(mask)-1 ----------------
__global__ __launch_bounds__(256) void init_kernel(const float* __restrict__ mask,
    float* __restrict__ h, float* __restrict__ c,
    int* __restrict__ sprev, int* __restrict__ eprev){
  int b = blockIdx.x, tid = threadIdx.x;
  __shared__ float red[256];
  float s = 0.f;
  for (int i=tid;i<NS;i+=256) s += mask[(size_t)b*NS+i];
  red[tid]=s; __syncthreads();
  for (int st=128;st>0;st>>=1){ if(tid<st) red[tid]+=red[tid+st]; __syncthreads(); }
  if (tid==0){ sprev[b]=0; eprev[b]=(int)red[0]-1; }
  for (int i=tid;i<NH;i+=256){ h[(size_t)b*NH+i]=0.f; c[(size_t)b*NH+i]=0.f; }
}

// ---------------- conversions / prep (pads folded in) ----------------
// mod [12800][400] f32 -> modExp [12800][1280] bf16 [hi|lo|hi|0]
__global__ __launch_bounds__(256) void conv_mod_k(const float* __restrict__ in, ushort* __restrict__ out){
  for (size_t i = (size_t)blockIdx.x*256+threadIdx.x; i < (size_t)NBS*K1; i += (size_t)gridDim.x*256){
    int r = (int)(i/K1), k = (int)(i%K1);
    ushort v = 0;
    if (k < 3*NM){
      float x = in[(size_t)r*NM + (k % NM)];
      ushort h = f2bf(x);
      v = (k < NM || k >= 2*NM) ? h : f2bf(x - bf2f(h));
    }
    out[i] = v;
  }
}
// W1 [3200][600] -> W1exp [3200][1280] rows permuted jp=h*16+p, [hi|hi|lo|0]; cols 0..400
__global__ __launch_bounds__(256) void conv_w1_k(const float* __restrict__ in, ushort* __restrict__ out){
  for (size_t i = (size_t)blockIdx.x*256+threadIdx.x; i < (size_t)NPH*K1; i += (size_t)gridDim.x*256){
    int jp = (int)(i/K1), k = (int)(i%K1);
    int j = (jp&15)*NH + (jp>>4);
    ushort v = 0;
    if (k < 3*NM){
      float x = in[(size_t)j*(NM+NH) + (k % NM)];
      ushort h = f2bf(x);
      v = (k < 2*NM) ? h : f2bf(x - bf2f(h));
    }
    out[i] = v;
  }
}
// W2 [3200][200] -> W2exp [3200][640] rows permuted, [hi|hi|lo|0]
__global__ __launch_bounds__(256) void conv_w2_k(const float* __restrict__ in, ushort* __restrict__ out){
  for (size_t i = (size_t)blockIdx.x*256+threadIdx.x; i < (size_t)NPH*K2; i += (size_t)gridDim.x*256){
    int jp = (int)(i/K2), k = (int)(i%K2);
    int j = (jp&15)*NH + (jp>>4);
    ushort v = 0;
    if (k < 3*NH){
      float x = in[(size_t)j*NH + (k % NH)];
      ushort h = f2bf(x);
      v = (k < 2*NH) ? h : f2bf(x - bf2f(h));
    }
    out[i] = v;
  }
}
// W1rT[k][jp] = W1[j][400+k], jp-permuted; k<200, jp<3200
__global__ __launch_bounds__(256) void conv_w1r_k(const float* __restrict__ in, float* __restrict__ out){
  for (size_t i = (size_t)blockIdx.x*256+threadIdx.x; i < (size_t)NH*NPH; i += (size_t)gridDim.x*256){
    int k = (int)(i/NPH), jp = (int)(i%NPH);
    int hh = jp>>4, p = jp&15, j = p*NH + hh;
    out[i] = in[(size_t)j*(NM+NH) + NM + k];
  }
}
__global__ __launch_bounds__(256) void permv_k(const float* __restrict__ in, float* __restrict__ out){
  int i = blockIdx.x*256+threadIdx.x;
  if (i < NPH) out[(i%NH)*NP + i/NH] = in[i];
}
__global__ __launch_bounds__(256) void pad_zero_k(ushort* __restrict__ p, int stride, int start, int width, int rows){
  for (size_t i = (size_t)blockIdx.x*256+threadIdx.x; i < (size_t)rows*width; i += (size_t)gridDim.x*256){
    int r = (int)(i/width), j = (int)(i%width);
    p[(size_t)r*stride + start + j] = 0;
  }
}

// ---------------- LSTM gates (wave per gate) ----------------
__global__ __launch_bounds__(256) void lstm_gates(const float* __restrict__ mod,
    const int* __restrict__ sprev, const int* __restrict__ eprev,
    const float* __restrict__ h,
    const float* __restrict__ Wih, const float* __restrict__ Whh,
    const float* __restrict__ bih, const float* __restrict__ bhh,
    float* __restrict__ gs){
  int b=blockIdx.x, tid=threadIdx.x;
  __shared__ float xs[NX+NH];
  const float* us = mod + ((size_t)b*NS + sprev[b])*NM;
  const float* ue = mod + ((size_t)b*NS + eprev[b])*NM;
  for (int i=tid;i<NM;i+=256){ xs[i]=us[i]; xs[NM+i]=ue[i]; }
  for (int i=tid;i<NH;i+=256) xs[NX+i]=h[(size_t)b*NH+i];
  __syncthreads();
  int w=tid>>6, lane=tid&63;
  int j = blockIdx.y*4 + w;                 // gridDim.y = 200 -> j < 800
  const float* wih = Wih + (size_t)j*NX;
  const float* whh = Whh + (size_t)j*NH;
  float acc=0.f;
  for (int k=lane;k<NX;k+=64) acc += xs[k]*wih[k];
  for (int k=lane;k<NH;k+=64) acc += xs[NX+k]*whh[k];
  acc = wave_sum(acc);
  if (lane==0) gs[(size_t)b*NG+j] = acc + bih[j] + bhh[j];
}

// ---- fused: (optional LSTM update) + r=tanh([h,us,ue]@rW^T) + prer ----
__global__ __launch_bounds__(512) void rprer_kernel(const float* __restrict__ mod,
    const int* __restrict__ sprev, const int* __restrict__ eprev,
    const float* __restrict__ gsb, float* __restrict__ h, float* __restrict__ c,
    const float* __restrict__ rW, const float* __restrict__ W1rT,
    const float* __restrict__ b1p, float* __restrict__ prer, int doUpdate){
  int b=blockIdx.x, tid=threadIdx.x;
  __shared__ float zs[NR];
  __shared__ float rsh[NH];
  if (doUpdate){
    if (tid < NH){
      float iv=gsb[(size_t)b*NG+tid], fv=gsb[(size_t)b*NG+NH+tid];
      float gv=gsb[(size_t)b*NG+2*NH+tid], ov=gsb[(size_t)b*NG+3*NH+tid];
      float c2 = sigf(fv)*c[(size_t)b*NH+tid] + sigf(iv)*tanhf(gv);
      float h2 = sigf(ov)*tanhf(c2);
      c[(size_t)b*NH+tid]=c2; h[(size_t)b*NH+tid]=h2;
      zs[tid]=h2;
    }
  } else {
    if (tid < NH) zs[tid] = h[(size_t)b*NH+tid];
  }
  const float* us = mod + ((size_t)b*NS + sprev[b])*NM;
  const float* ue = mod + ((size_t)b*NS + eprev[b])*NM;
  for (int i=tid;i<NM;i+=512){ zs[NH+i]=us[i]; zs[NH+NM+i]=ue[i]; }
  __syncthreads();
  int w=tid>>6, lane=tid&63;                // 8 waves
  for (int jj=0; jj<25; jj++){
    int j = w*25 + jj;
    const float* wr = rW + (size_t)j*NR;
    float acc=0.f;
    for (int k=lane;k<NR;k+=64) acc += zs[k]*wr[k];
    acc = wave_sum(acc);
    if (lane==0) rsh[j] = tanhf(acc);
  }
  __syncthreads();
  for (int jp=tid; jp<NPH; jp+=512){
    float acc = b1p[jp];
    #pragma unroll 8
    for (int k=0;k<NH;k++) acc += rsh[k]*W1rT[(size_t)k*NPH + jp];
    prer[(size_t)b*NPH + jp] = acc;
  }
}

// ------------- fused bf16-split GEMM + bias + max-over-P, 3-buf prefetch-2 -------------
template<int MODE>
__global__ __launch_bounds__(256) void gemm_fused(
    const ushort* __restrict__ A, const ushort* __restrict__ W, int ldk,
    const float* __restrict__ bias, void* __restrict__ outp){
  __shared__ __align__(16) ushort As[3][128*32];
  __shared__ __align__(16) ushort Bs[3][128*32];
  __shared__ float biasLds[2][128];
  __shared__ float outT[128][8];
  const int tid = threadIdx.x;
  const int i0 = blockIdx.x*128, j0 = blockIdx.y*128;
  const int b0 = i0/NS;
  if (MODE==0){
    if (tid<128) biasLds[0][tid] = bias[(size_t)b0*NPH + j0 + tid];
    else { int b1r = (i0+127)/NS; biasLds[1][tid-128] = bias[(size_t)b1r*NPH + j0 + (tid-128)]; }
  } else {
    if (tid<128) biasLds[0][tid] = bias[j0+tid];
  }
  const int l = tid&63, w = tid>>6;
  const int wr = w>>1, wc = w&1;             // 2x2 waves, 64x64 each
  const int srow = tid>>2, slot = tid&3;     // staging: 4 lanes/row
  const int fr = l&15, fk = l>>4;            // fragment row/k-group
  const int ksteps = ldk>>5;
  // precomputed per-thread staging pointers (pre-swizzled source, linear LDS dest)
  const int ss0 = slot ^ ((srow>>1)&3);
  const int ss1 = slot ^ (((srow+64)>>1)&3);
  const ushort* gA0 = A + (size_t)(i0+srow)*ldk     + ss0*8;
  const ushort* gA1 = A + (size_t)(i0+srow+64)*ldk  + ss1*8;
  const ushort* gB0 = W + (size_t)(j0+srow)*ldk     + ss0*8;
  const ushort* gB1 = W + (size_t)(j0+srow+64)*ldk  + ss1*8;
  const int ldsOff = srow*32 + slot*8;       // == tid*8 (linear in lane)
  auto stage = [&](int buf, int kt){
    __builtin_amdgcn_global_load_lds((const __attribute__((address_space(1))) void*)(gA0 + kt*32),
        (__attribute__((address_space(3))) void*)(&As[buf][ldsOff]), 16, 0, 0);
    __builtin_amdgcn_global_load_lds((const __attribute__((address_space(1))) void*)(gB0 + kt*32),
        (__attribute__((address_space(3))) void*)(&Bs[buf][ldsOff]), 16, 0, 0);
    __builtin_amdgcn_global_load_lds((const __attribute__((address_space(1))) void*)(gA1 + kt*32),
        (__attribute__((address_space(3))) void*)(&As[buf][64*32 + ldsOff]), 16, 0, 0);
    __builtin_amdgcn_global_load_lds((const __attribute__((address_space(1))) void*)(gB1 + kt*32),
        (__attribute__((address_space(3))) void*)(&Bs[buf][64*32 + ldsOff]), 16, 0, 0);
  };
  f32x4 acc[4][4] = {};
  stage(0, 0);
  if (ksteps > 1) stage(1, 1);
  __syncthreads();                            // full drain once (prologue only)
  for (int kt=0; kt<ksteps; kt++){
    // wait: tile kt landed. outstanding here = tile kt (maybe) + tile kt+1 (4 insts).
    if (kt+1 < ksteps) asm volatile("s_waitcnt vmcnt(4)" ::: "memory");
    else               asm volatile("s_waitcnt vmcnt(0)" ::: "memory");
    __builtin_amdgcn_s_barrier();
    const int cur = kt % 3;
    short8v af[4], bf[4];
    #pragma unroll
    for (int m=0;m<4;m++){
      int row = wr*64 + m*16 + fr;
      int sl = fk ^ ((row>>1)&3);
      af[m] = *(const short8v*)(&As[cur][row*32 + sl*8]);
    }
    #pragma unroll
    for (int n=0;n<4;n++){
      int row = wc*64 + n*16 + fr;
      int sl = fk ^ ((row>>1)&3);
      bf[n] = *(const short8v*)(&Bs[cur][row*32 + sl*8]);
    }
    asm volatile("s_waitcnt lgkmcnt(0)" ::: "memory");   // reads of buf cur complete
    __builtin_amdgcn_sched_barrier(0);
    if (kt+2 < ksteps) stage((kt+2)%3, kt+2);            // overwrites buf (kt-1)%3: safe
    #pragma unroll
    for (int m=0;m<4;m++)
      #pragma unroll
      for (int n=0;n<4;n++)
        acc[m][n] = __builtin_amdgcn_mfma_f32_16x16x32_bf16(af[m], bf[n], acc[m][n], 0,0,0);
  }
  __syncthreads();
  // epilogue: bias + max over the 16 cols (=p) of each 16x16 fragment
  const int blim = (b0+1)*NS;
  #pragma unroll
  for (int m=0;m<4;m++){
    #pragma unroll
    for (int n=0;n<4;n++){
      int colL = wc*64 + n*16 + fr;
      int rbase = wr*64 + m*16 + fk*4;
      #pragma unroll
      for (int reg=0; reg<4; reg++){
        int rowL = rbase + reg;
        float bv;
        if (MODE==0) bv = ((i0+rowL) >= blim) ? biasLds[1][colL] : biasLds[0][colL];
        else bv = biasLds[0][colL];
        float v = acc[m][n][reg] + bv;
        v = fmaxf(v, __shfl_xor(v,1));
        v = fmaxf(v, __shfl_xor(v,2));
        v = fmaxf(v, __shfl_xor(v,4));
        v = fmaxf(v, __shfl_xor(v,8));
        if (fr==0) outT[rowL][wc*4+n] = v;
      }
    }
  }
  __syncthreads();
  {
    int rowL = tid>>1;
    int c4 = (tid&1)*4;
    int absrow = i0 + rowL;
    int hg0 = (j0>>4) + c4;
    float v0=outT[rowL][c4], v1=outT[rowL][c4+1], v2=outT[rowL][c4+2], v3=outT[rowL][c4+3];
    if (MODE==0){
      ushort* o = (ushort*)outp + (size_t)absrow*K2 + hg0;
      ushort h0=f2bf(v0), h1=f2bf(v1), h2=f2bf(v2), h3=f2bf(v3);
      ushort l0=f2bf(v0-bf2f(h0)), l1=f2bf(v1-bf2f(h1)), l2=f2bf(v2-bf2f(h2)), l3=f2bf(v3-bf2f(h3));
      *(us4*)(o)        = (us4){h0,h1,h2,h3};
      *(us4*)(o+NH)     = (us4){l0,l1,l2,l3};
      *(us4*)(o+2*NH)   = (us4){h0,h1,h2,h3};
    } else {
      float* o = (float*)outp + (size_t)absrow*NH + hg0;
      *(f32x4*)o = (f32x4){v0,v1,v2,v3};
    }
  }
}

// --------- fused logits: maxout-3 + mask + log_softmax + argmax; block per b ---------
__global__ __launch_bounds__(512) void logits_kernel(const ushort* __restrict__ m1e,
    const float* __restrict__ m2, const float* __restrict__ W3, const float* __restrict__ b3,
    const float* __restrict__ mask, float* __restrict__ out, int t, int* __restrict__ prevIdx){
  int b=blockIdx.x, tid=threadIdx.x;
  __shared__ float lg[NS];
  if (tid < NS){
    int s = tid;
    const ushort* a = m1e + (size_t)(b*NS+s)*K2;
    const float4* d = (const float4*)(m2 + (size_t)(b*NS+s)*NH);
    float acc[NP];
    #pragma unroll
    for (int p=0;p<NP;p++) acc[p]=b3[p];
    for (int k=0;k<NH/4;k++){
      us4 hv = *(const us4*)(a + 4*k);
      us4 lv = *(const us4*)(a + NH + 4*k);
      float4 dv = d[k];
      float a0=bf2f(hv.x)+bf2f(lv.x), a1=bf2f(hv.y)+bf2f(lv.y);
      float a2=bf2f(hv.z)+bf2f(lv.z), a3=bf2f(hv.w)+bf2f(lv.w);
      #pragma unroll
      for (int p=0;p<NP;p++){
        const float* wp = W3 + p*(2*NH) + 4*k;        // wave-uniform -> s_load
        acc[p] += a0*wp[0]+a1*wp[1]+a2*wp[2]+a3*wp[3];
        const float* w2 = wp + NH;
        acc[p] += dv.x*w2[0]+dv.y*w2[1]+dv.z*w2[2]+dv.w*w2[3];
      }
    }
    float best=acc[0];
    #pragma unroll
    for (int p=1;p<NP;p++) best=fmaxf(best,acc[p]);
    lg[s] = (mask[(size_t)b*NS+s] > 0.f) ? best : -1e30f;
  }
  __syncthreads();
  __shared__ float rv[512]; __shared__ int ri[512]; __shared__ float sv[512];
  float bv=-INFINITY; int bi=NS;
  if (tid < NS){ bv = lg[tid]; bi = tid; }
  rv[tid]=bv; ri[tid]=bi; __syncthreads();
  for (int st=256;st>0;st>>=1){
    if (tid<st){
      float v2=rv[tid+st]; int i2=ri[tid+st];
      if (v2>rv[tid] || (v2==rv[tid] && i2<ri[tid])){ rv[tid]=v2; ri[tid]=i2; }
    }
    __syncthreads();
  }
  float mx = rv[0];
  float ps = (tid<NS) ? expf(lg[tid]-mx) : 0.f;
  sv[tid]=ps; __syncthreads();
  for (int st=256;st>0;st>>=1){ if (tid<st) sv[tid]+=sv[tid+st]; __syncthreads(); }
  float lse = mx + logf(sv[0]);
  if (tid < NS) out[((size_t)b*NT + t)*NS + tid] = lg[tid]-lse;
  if (tid==0) prevIdx[b]=ri[0];
}

// =============================== host ===============================
extern "C" void kernel_launch(void* const* d_in, const int* in_sizes, int n_in,
                              void* d_out, int out_size, void* d_ws, size_t ws_size,
                              hipStream_t stream){
  const float* mod  = (const float*)d_in[1];
  const float* mask = (const float*)d_in[2];
  const float* Wih  = (const float*)d_in[3];
  const float* Whh  = (const float*)d_in[4];
  const float* bih  = (const float*)d_in[5];
  const float* bhh  = (const float*)d_in[6];
  const float* rW[2] = {(const float*)d_in[7],  (const float*)d_in[14]};
  const float* W1[2] = {(const float*)d_in[8],  (const float*)d_in[15]};
  const float* b1[2] = {(const float*)d_in[9],  (const float*)d_in[16]};
  const float* W2[2] = {(const float*)d_in[10], (const float*)d_in[17]};
  const float* b2[2] = {(const float*)d_in[11], (const float*)d_in[18]};
  const float* W3[2] = {(const float*)d_in[12], (const float*)d_in[19]};
  const float* b3[2] = {(const float*)d_in[13], (const float*)d_in[20]};
  float* out[2];
  out[0] = (float*)d_out;
  out[1] = out[0] + (size_t)NB*NT*NS;

  float* wsf = (float*)d_ws;
  size_t off = 0;
  auto carve = [&](size_t n)->size_t{ size_t o=off; off += (n + 63) & ~(size_t)63; return o; };
  float* hbuf   = wsf + carve((size_t)NB*NH);
  float* cbuf   = wsf + carve((size_t)NB*NH);
  float* prer   = wsf + carve((size_t)NB*NPH);
  int*   sprev  = (int*)(wsf + carve(128));
  int*   eprev  = sprev + 32;
  float* m2f    = wsf + carve((size_t)NBS*NH);
  float* b2p[2] = {wsf + carve(NPH), wsf + carve(NPH)};
  float* b1p[2] = {wsf + carve(NPH), wsf + carve(NPH)};
  float* gsbuf  = wsf + carve((size_t)NB*NG);
  float* W1rT[2]= {wsf + carve((size_t)NH*NPH), wsf + carve((size_t)NH*NPH)};
  ushort* modExp   = (ushort*)(wsf + carve((size_t)NBS*K1/2));
  ushort* W1exp[2] = {(ushort*)(wsf + carve((size_t)NPH*K1/2)),
                      (ushort*)(wsf + carve((size_t)NPH*K1/2))};
  ushort* W2exp[2] = {(ushort*)(wsf + carve((size_t)NPH*K2/2)),
                      (ushort*)(wsf + carve((size_t)NPH*K2/2))};
  ushort* m1exp    = (ushort*)(wsf + carve((size_t)NBS*K2/2));

  // ---- init + prep (every launch; deterministic) ----
  init_kernel<<<NB, 256, 0, stream>>>(mask, hbuf, cbuf, sprev, eprev);
  conv_mod_k<<<2048, 256, 0, stream>>>(mod, modExp);
  pad_zero_k<<<256, 256, 0, stream>>>(m1exp, K2, 3*NH, K2-3*NH, NBS);
  for (int net=0; net<2; net++){
    conv_w1_k<<<2048, 256, 0, stream>>>(W1[net], W1exp[net]);
    conv_w2_k<<<1024, 256, 0, stream>>>(W2[net], W2exp[net]);
    conv_w1r_k<<<1024, 256, 0, stream>>>(W1[net], W1rT[net]);
    permv_k<<<(NPH+255)/256, 256, 0, stream>>>(b2[net], b2p[net]);
    permv_k<<<(NPH+255)/256, 256, 0, stream>>>(b1[net], b1p[net]);
  }

  dim3 ggrid(NBS/128, NPH/128);
  for (int t=0; t<NT; t++){
    lstm_gates<<<dim3(NB, NG/4), 256, 0, stream>>>(mod, sprev, eprev, hbuf,
                                                   Wih, Whh, bih, bhh, gsbuf);
    for (int net=0; net<2; net++){
      rprer_kernel<<<NB, 512, 0, stream>>>(mod, sprev, eprev, gsbuf, hbuf, cbuf,
                                           rW[net], W1rT[net], b1p[net], prer, net==0);
      gemm_fused<0><<<ggrid, 256, 0, stream>>>(modExp, W1exp[net], K1, prer, (void*)m1exp);
      gemm_fused<1><<<ggrid, 256, 0, stream>>>(m1exp, W2exp[net], K2, b2p[net], (void*)m2f);
      logits_kernel<<<NB, 512, 0, stream>>>(m1exp, m2f, W3[net], b3[net], mask,
                                            out[net], t, net==0 ? sprev : eprev);
    }
  }
}

// Round 5
// 3331.778 us; speedup vs baseline: 1.3757x; 1.3757x over previous
//
#include <hip/hip_runtime.h>
#include <math.h>

#define NB 32
#define NS 400
#define NM 400
#define NH 200
#define NP 16
#define NT 4
#define NBS (NB*NS)          // 12800
#define NPH (NP*NH)          // 3200
#define NPH2 3328            // padded N (13*256)
#define NX  (2*NM)           // 800
#define NG  (4*NH)           // 800
#define NR  (2*NM+NH)        // 1000
#define K1  1280             // m1 GEMM K' (3*400 padded to /64)
#define K2  640              // m2 GEMM K' (3*200 padded to /64)

typedef __attribute__((ext_vector_type(8))) short short8v;
typedef __attribute__((ext_vector_type(4))) float f32x4;
typedef __attribute__((ext_vector_type(4))) unsigned short us4;
typedef unsigned short ushort;

__device__ __forceinline__ float sigf(float x){ return 1.0f/(1.0f+expf(-x)); }

__device__ __forceinline__ ushort f2bf(float x){
  union{float f; unsigned u;} v; v.f=x;
  unsigned r = v.u + 0x7fffu + ((v.u>>16)&1u);
  return (ushort)(r>>16);
}
__device__ __forceinline__ float bf2f(ushort u){
  union{float f; unsigned v;} x; x.v = ((unsigned)u)<<16; return x.f;
}
__device__ __forceinline__ float wave_sum(float v){
  #pragma unroll
  for (int o=32;o>0;o>>=1) v += __shfl_xor(v, o);
  return v;
}

// ---------------- init: h=c=0, sprev=0, eprev=sum(mask)-1 ----------------
__global__ __launch_bounds__(256) void init_kernel(const float* __restrict__ mask,
    float* __restrict__ h, float* __restrict__ c,
    int* __restrict__ sprev, int* __restrict__ eprev){
  int b = blockIdx.x, tid = threadIdx.x;
  __shared__ float red[256];
  float s = 0.f;
  for (int i=tid;i<NS;i+=256) s += mask[(size_t)b*NS+i];
  red[tid]=s; __syncthreads();
  for (int st=128;st>0;st>>=1){ if(tid<st) red[tid]+=red[tid+st]; __syncthreads(); }
  if (tid==0){ sprev[b]=0; eprev[b]=(int)red[0]-1; }
  for (int i=tid;i<NH;i+=256){ h[(size_t)b*NH+i]=0.f; c[(size_t)b*NH+i]=0.f; }
}

// ---------------- conversions / prep ----------------
// mod [12800][400] f32 -> modExp [12800][1280] bf16 [hi|lo|hi|0]
__global__ __launch_bounds__(256) void conv_mod_k(const float* __restrict__ in, ushort* __restrict__ out){
  for (size_t i = (size_t)blockIdx.x*256+threadIdx.x; i < (size_t)NBS*K1; i += (size_t)gridDim.x*256){
    int r = (int)(i/K1), k = (int)(i%K1);
    ushort v = 0;
    if (k < 3*NM){
      float x = in[(size_t)r*NM + (k % NM)];
      ushort h = f2bf(x);
      v = (k < NM || k >= 2*NM) ? h : f2bf(x - bf2f(h));
    }
    out[i] = v;
  }
}
// W1 [3200][600] -> W1exp [3328][1280] rows permuted jp=h*16+p, [hi|hi|lo|0]; rows>=3200 zero
__global__ __launch_bounds__(256) void conv_w1_k(const float* __restrict__ in, ushort* __restrict__ out){
  for (size_t i = (size_t)blockIdx.x*256+threadIdx.x; i < (size_t)NPH2*K1; i += (size_t)gridDim.x*256){
    int jp = (int)(i/K1), k = (int)(i%K1);
    ushort v = 0;
    if (jp < NPH && k < 3*NM){
      int j = (jp&15)*NH + (jp>>4);
      float x = in[(size_t)j*(NM+NH) + (k % NM)];
      ushort h = f2bf(x);
      v = (k < 2*NM) ? h : f2bf(x - bf2f(h));
    }
    out[i] = v;
  }
}
// W2 [3200][200] -> W2exp [3328][640]
__global__ __launch_bounds__(256) void conv_w2_k(const float* __restrict__ in, ushort* __restrict__ out){
  for (size_t i = (size_t)blockIdx.x*256+threadIdx.x; i < (size_t)NPH2*K2; i += (size_t)gridDim.x*256){
    int jp = (int)(i/K2), k = (int)(i%K2);
    ushort v = 0;
    if (jp < NPH && k < 3*NH){
      int j = (jp&15)*NH + (jp>>4);
      float x = in[(size_t)j*NH + (k % NH)];
      ushort h = f2bf(x);
      v = (k < 2*NH) ? h : f2bf(x - bf2f(h));
    }
    out[i] = v;
  }
}
// W1rT[k][jp] = W1[j][400+k], jp-permuted; k<200, jp<3200
__global__ __launch_bounds__(256) void conv_w1r_k(const float* __restrict__ in, float* __restrict__ out){
  for (size_t i = (size_t)blockIdx.x*256+threadIdx.x; i < (size_t)NH*NPH; i += (size_t)gridDim.x*256){
    int k = (int)(i/NPH), jp = (int)(i%NPH);
    int hh = jp>>4, p = jp&15, j = p*NH + hh;
    out[i] = in[(size_t)j*(NM+NH) + NM + k];
  }
}
// permute bias vector into jp order, pad to NPH2 with zeros
__global__ __launch_bounds__(256) void permv_k(const float* __restrict__ in, float* __restrict__ out){
  int i = blockIdx.x*256+threadIdx.x;
  if (i < NPH) out[(i%NH)*NP + i/NH] = in[i];
  else if (i < NPH2) out[i] = 0.f;
}
__global__ __launch_bounds__(256) void pad_zero_k(ushort* __restrict__ p, int stride, int start, int width, int rows){
  for (size_t i = (size_t)blockIdx.x*256+threadIdx.x; i < (size_t)rows*width; i += (size_t)gridDim.x*256){
    int r = (int)(i/width), j = (int)(i%width);
    p[(size_t)r*stride + start + j] = 0;
  }
}

// ---------------- LSTM gates (wave per gate) ----------------
__global__ __launch_bounds__(256) void lstm_gates(const float* __restrict__ mod,
    const int* __restrict__ sprev, const int* __restrict__ eprev,
    const float* __restrict__ h,
    const float* __restrict__ Wih, const float* __restrict__ Whh,
    const float* __restrict__ bih, const float* __restrict__ bhh,
    float* __restrict__ gs){
  int b=blockIdx.x, tid=threadIdx.x;
  __shared__ float xs[NX+NH];
  const float* us = mod + ((size_t)b*NS + sprev[b])*NM;
  const float* ue = mod + ((size_t)b*NS + eprev[b])*NM;
  for (int i=tid;i<NM;i+=256){ xs[i]=us[i]; xs[NM+i]=ue[i]; }
  for (int i=tid;i<NH;i+=256) xs[NX+i]=h[(size_t)b*NH+i];
  __syncthreads();
  int w=tid>>6, lane=tid&63;
  int j = blockIdx.y*4 + w;                 // gridDim.y = 200 -> j < 800
  const float* wih = Wih + (size_t)j*NX;
  const float* whh = Whh + (size_t)j*NH;
  float acc=0.f;
  for (int k=lane;k<NX;k+=64) acc += xs[k]*wih[k];
  for (int k=lane;k<NH;k+=64) acc += xs[NX+k]*whh[k];
  acc = wave_sum(acc);
  if (lane==0) gs[(size_t)b*NG+j] = acc + bih[j] + bhh[j];
}
__global__ __launch_bounds__(256) void lstm_update(const float* __restrict__ gs,
    float* __restrict__ h, float* __restrict__ c){
  int b=blockIdx.x, j=threadIdx.x;
  if (j<NH){
    float iv=gs[(size_t)b*NG+j], fv=gs[(size_t)b*NG+NH+j];
    float gv=gs[(size_t)b*NG+2*NH+j], ov=gs[(size_t)b*NG+3*NH+j];
    float c2 = sigf(fv)*c[(size_t)b*NH+j] + sigf(iv)*tanhf(gv);
    c[(size_t)b*NH+j]=c2;
    h[(size_t)b*NH+j]=sigf(ov)*tanhf(c2);
  }
}

// ---------------- r = tanh([h,us,ue]@rW^T), wave per output ----------------
__global__ __launch_bounds__(256) void r_kernel(const float* __restrict__ mod,
    const int* __restrict__ sprev, const int* __restrict__ eprev,
    const float* __restrict__ h, const float* __restrict__ rW,
    float* __restrict__ rbuf){
  int b=blockIdx.x, tid=threadIdx.x;
  __shared__ float zs[NR];
  const float* us = mod + ((size_t)b*NS + sprev[b])*NM;
  const float* ue = mod + ((size_t)b*NS + eprev[b])*NM;
  for (int i=tid;i<NH;i+=256) zs[i]=h[(size_t)b*NH+i];
  for (int i=tid;i<NM;i+=256){ zs[NH+i]=us[i]; zs[NH+NM+i]=ue[i]; }
  __syncthreads();
  int w=tid>>6, lane=tid&63;
  int j = blockIdx.y*4 + w;                 // gridDim.y = 50 -> j < 200
  const float* wr = rW + (size_t)j*NR;
  float acc=0.f;
  for (int k=lane;k<NR;k+=64) acc += zs[k]*wr[k];
  acc = wave_sum(acc);
  if (lane==0) rbuf[(size_t)b*NH+j] = tanhf(acc);
}

// ---------------- prer[b][jp] = b1p[jp] + sum_k r[b][k]*W1rT[k][jp]; padded N ----------------
__global__ __launch_bounds__(256) void prer_kernel(const float* __restrict__ rbuf,
    const float* __restrict__ W1rT, const float* __restrict__ b1p,
    float* __restrict__ prer){
  int b=blockIdx.x, tid=threadIdx.x;
  __shared__ float rs[NH];
  if (tid < NH) rs[tid] = rbuf[(size_t)b*NH+tid];
  __syncthreads();
  int jp = blockIdx.y*256 + tid;
  if (jp < NPH2){
    float acc = 0.f;
    if (jp < NPH){
      acc = b1p[jp];
      #pragma unroll 8
      for (int k=0;k<NH;k++) acc += rs[k]*W1rT[(size_t)k*NPH + jp];
    }
    prer[(size_t)b*NPH2 + jp] = acc;
  }
}

// ------------- fused bf16-split GEMM + bias + max-over-P -------------
// 256x256 tile, 8 waves (2M x 4N), wave tile 128x64, BK=64, counted-vmcnt pipeline.
// Schedule per K-tile t (slot t&1):
//   vmcnt(8 | 0) ; s_barrier          -> tile t landed for ALL waves (RAW safe)
//   48 ds_read + 64 MFMA (compiler-scheduled, setprio around MFMA clusters)
//   lgkmcnt(0) ; s_barrier            -> all waves done reading slot
//   stage(tile t+2 -> this slot)      -> WAR safe; ~1 full iter in flight before use
template<int MODE>
__global__ __launch_bounds__(512, 2) void gemm_fused(
    const ushort* __restrict__ A, const ushort* __restrict__ W,
    const float* __restrict__ bias, void* __restrict__ outp){
  constexpr int LDK = (MODE==0) ? K1 : K2;
  constexpr int NTI = LDK/64;
  __shared__ __align__(16) ushort As[2][256*64];
  __shared__ __align__(16) ushort Bs[2][256*64];
  __shared__ float biasLds[2][256];
  __shared__ float outT[256][16];
  const int tid = threadIdx.x;
  const int i0 = blockIdx.x*256, j0 = blockIdx.y*256;
  const int b0 = i0/NS;
  if (MODE==0){
    if (tid<256) biasLds[0][tid] = bias[(size_t)b0*NPH2 + j0 + tid];
    else { int b1r=(i0+255)/NS; biasLds[1][tid-256] = bias[(size_t)b1r*NPH2 + j0 + (tid-256)]; }
  } else {
    if (tid<256) biasLds[0][tid] = bias[j0+tid];
  }
  const int w = tid>>6, l = tid&63;
  const int wr = w>>2, wc = w&3;            // 2M x 4N waves, wave tile 128x64
  const int fr = l&15, fk = l>>4;
  // staging: wave w rows w*32 + j*8 + (l>>3); LDS linear dest; XOR-swizzled global source.
  // LDS[row][cu] = G[row][kt*64 + (cu ^ ((row&7)<<3))]   (cu = ushort col)
  const int swz = ((l&7) ^ (l>>3))*8;       // ushort units
  const ushort* gA = A + (size_t)(i0 + w*32 + (l>>3))*LDK + swz;
  const ushort* gB = W + (size_t)(j0 + w*32 + (l>>3))*LDK + swz;
  const int wOff = w*2048 + l*8;            // == row*64 + (l&7)*8
  auto stage = [&](int slot, int kt){
    const ushort* a0 = gA + kt*64;
    const ushort* b0g = gB + kt*64;
    #pragma unroll
    for (int j=0;j<4;j++)
      __builtin_amdgcn_global_load_lds((const __attribute__((address_space(1))) void*)(a0 + (size_t)j*8*LDK),
          (__attribute__((address_space(3))) void*)(&As[slot][wOff + j*512]), 16, 0, 0);
    #pragma unroll
    for (int j=0;j<4;j++)
      __builtin_amdgcn_global_load_lds((const __attribute__((address_space(1))) void*)(b0g + (size_t)j*8*LDK),
          (__attribute__((address_space(3))) void*)(&Bs[slot][wOff + j*512]), 16, 0, 0);
  };
  f32x4 acc[8][4] = {};
  stage(0, 0);
  stage(1, 1);
  const int koffA = (fr&7)<<3;
  for (int t=0; t<NTI; t++){
    const int s = t&1;
    if (t+1 < NTI) asm volatile("s_waitcnt vmcnt(8)" ::: "memory");
    else           asm volatile("s_waitcnt vmcnt(0)" ::: "memory");
    __builtin_amdgcn_s_barrier();
    #pragma unroll
    for (int ks=0; ks<2; ks++){
      const int ko = (ks*32 + fk*8) ^ koffA;
      short8v a[8], b[4];
      #pragma unroll
      for (int m=0;m<8;m++) a[m] = *(const short8v*)&As[s][(wr*128 + m*16 + fr)*64 + ko];
      #pragma unroll
      for (int n=0;n<4;n++) b[n] = *(const short8v*)&Bs[s][(wc*64 + n*16 + fr)*64 + ko];
      __builtin_amdgcn_s_setprio(1);
      #pragma unroll
      for (int m=0;m<8;m++)
        #pragma unroll
        for (int n=0;n<4;n++)
          acc[m][n] = __builtin_amdgcn_mfma_f32_16x16x32_bf16(a[m], b[n], acc[m][n], 0,0,0);
      __builtin_amdgcn_s_setprio(0);
    }
    asm volatile("s_waitcnt lgkmcnt(0)" ::: "memory");
    __builtin_amdgcn_s_barrier();
    if (t+2 < NTI) stage(s, t+2);
  }
  __syncthreads();
  // epilogue: bias + max over the 16 cols (=p) of each 16x16 fragment
  const int blim = (b0+1)*NS;
  #pragma unroll
  for (int m=0;m<8;m++){
    #pragma unroll
    for (int n=0;n<4;n++){
      int colL = wc*64 + n*16 + fr;
      int rbase = wr*128 + m*16 + fk*4;
      #pragma unroll
      for (int reg=0; reg<4; reg++){
        int rowL = rbase + reg;
        float bv = (MODE==0 && (i0+rowL) >= blim) ? biasLds[1][colL] : biasLds[0][colL];
        float v = acc[m][n][reg] + bv;
        v = fmaxf(v, __shfl_xor(v,1));
        v = fmaxf(v, __shfl_xor(v,2));
        v = fmaxf(v, __shfl_xor(v,4));
        v = fmaxf(v, __shfl_xor(v,8));
        if (fr==0) outT[rowL][wc*4+n] = v;
      }
    }
  }
  __syncthreads();
  {
    int rowL = tid>>1;
    int hloc0 = (tid&1)*8;
    int hg0 = (j0>>4) + hloc0;
    if (hg0 < NH){                          // padded-h tiles: skip stores beyond 200
      int absrow = i0 + rowL;
      float v[8];
      #pragma unroll
      for (int q=0;q<8;q++) v[q] = outT[rowL][hloc0+q];
      if (MODE==0){
        ushort* o = (ushort*)outp + (size_t)absrow*K2 + hg0;
        ushort hi[8], lo[8];
        #pragma unroll
        for (int q=0;q<8;q++){ hi[q]=f2bf(v[q]); lo[q]=f2bf(v[q]-bf2f(hi[q])); }
        *(us4*)(o)        = (us4){hi[0],hi[1],hi[2],hi[3]};
        *(us4*)(o+4)      = (us4){hi[4],hi[5],hi[6],hi[7]};
        *(us4*)(o+NH)     = (us4){lo[0],lo[1],lo[2],lo[3]};
        *(us4*)(o+NH+4)   = (us4){lo[4],lo[5],lo[6],lo[7]};
        *(us4*)(o+2*NH)   = (us4){hi[0],hi[1],hi[2],hi[3]};
        *(us4*)(o+2*NH+4) = (us4){hi[4],hi[5],hi[6],hi[7]};
      } else {
        float* o = (float*)outp + (size_t)absrow*NH + hg0;
        *(f32x4*)o     = (f32x4){v[0],v[1],v[2],v[3]};
        *(f32x4*)(o+4) = (f32x4){v[4],v[5],v[6],v[7]};
      }
    }
  }
}

// --------- logits main: one thread per s, grid (NB, 2) ---------
__global__ __launch_bounds__(256) void logits_main(const ushort* __restrict__ m1e,
    const float* __restrict__ m2, const float* __restrict__ W3, const float* __restrict__ b3,
    const float* __restrict__ mask, float* __restrict__ lg){
  int b=blockIdx.x;
  int s=blockIdx.y*256+threadIdx.x;
  if (s >= NS) return;
  const ushort* a = m1e + (size_t)(b*NS+s)*K2;
  const float4* d = (const float4*)(m2 + (size_t)(b*NS+s)*NH);
  float acc[NP];
  #pragma unroll
  for (int p=0;p<NP;p++) acc[p]=b3[p];
  for (int k=0;k<NH/4;k++){
    us4 hv = *(const us4*)(a + 4*k);
    us4 lv = *(const us4*)(a + NH + 4*k);
    float4 dv = d[k];
    float a0=bf2f(hv.x)+bf2f(lv.x), a1=bf2f(hv.y)+bf2f(lv.y);
    float a2=bf2f(hv.z)+bf2f(lv.z), a3=bf2f(hv.w)+bf2f(lv.w);
    #pragma unroll
    for (int p=0;p<NP;p++){
      const float* wp = W3 + p*(2*NH) + 4*k;        // wave-uniform -> s_load
      acc[p] += a0*wp[0]+a1*wp[1]+a2*wp[2]+a3*wp[3];
      const float* w2 = wp + NH;
      acc[p] += dv.x*w2[0]+dv.y*w2[1]+dv.z*w2[2]+dv.w*w2[3];
    }
  }
  float best=acc[0];
  #pragma unroll
  for (int p=1;p<NP;p++) best=fmaxf(best,acc[p]);
  lg[(size_t)b*NS+s] = (mask[(size_t)b*NS+s] > 0.f) ? best : -1e30f;
}

// --------- logits finish: log_softmax + argmax; one block per b ---------
__global__ __launch_bounds__(256) void logits_fin(const float* __restrict__ lg,
    float* __restrict__ out, int t, int* __restrict__ prevIdx){
  int b=blockIdx.x, tid=threadIdx.x;
  __shared__ float rv[256]; __shared__ int ri[256]; __shared__ float sv[256];
  float bv=-INFINITY; int bi=NS;
  for (int s=tid;s<NS;s+=256){ float v=lg[(size_t)b*NS+s]; if (v>bv){bv=v;bi=s;} }
  rv[tid]=bv; ri[tid]=bi; __syncthreads();
  for (int st=128;st>0;st>>=1){
    if (tid<st){
      float v2=rv[tid+st]; int i2=ri[tid+st];
      if (v2>rv[tid] || (v2==rv[tid] && i2<ri[tid])){ rv[tid]=v2; ri[tid]=i2; }
    }
    __syncthreads();
  }
  float mx = rv[0];
  float ps=0.f;
  for (int s=tid;s<NS;s+=256) ps += expf(lg[(size_t)b*NS+s]-mx);
  sv[tid]=ps; __syncthreads();
  for (int st=128;st>0;st>>=1){ if (tid<st) sv[tid]+=sv[tid+st]; __syncthreads(); }
  float lse = mx + logf(sv[0]);
  for (int s=tid;s<NS;s+=256) out[((size_t)b*NT + t)*NS + s] = lg[(size_t)b*NS+s]-lse;
  if (tid==0) prevIdx[b]=ri[0];
}

// =============================== host ===============================
extern "C" void kernel_launch(void* const* d_in, const int* in_sizes, int n_in,
                              void* d_out, int out_size, void* d_ws, size_t ws_size,
                              hipStream_t stream){
  const float* mod  = (const float*)d_in[1];
  const float* mask = (const float*)d_in[2];
  const float* Wih  = (const float*)d_in[3];
  const float* Whh  = (const float*)d_in[4];
  const float* bih  = (const float*)d_in[5];
  const float* bhh  = (const float*)d_in[6];
  const float* rW[2] = {(const float*)d_in[7],  (const float*)d_in[14]};
  const float* W1[2] = {(const float*)d_in[8],  (const float*)d_in[15]};
  const float* b1[2] = {(const float*)d_in[9],  (const float*)d_in[16]};
  const float* W2[2] = {(const float*)d_in[10], (const float*)d_in[17]};
  const float* b2[2] = {(const float*)d_in[11], (const float*)d_in[18]};
  const float* W3[2] = {(const float*)d_in[12], (const float*)d_in[19]};
  const float* b3[2] = {(const float*)d_in[13], (const float*)d_in[20]};
  float* out[2];
  out[0] = (float*)d_out;
  out[1] = out[0] + (size_t)NB*NT*NS;

  float* wsf = (float*)d_ws;
  size_t off = 0;
  auto carve = [&](size_t n)->size_t{ size_t o=off; off += (n + 63) & ~(size_t)63; return o; };
  float* hbuf   = wsf + carve((size_t)NB*NH);
  float* cbuf   = wsf + carve((size_t)NB*NH);
  float* prer   = wsf + carve((size_t)NB*NPH2);
  int*   sprev  = (int*)(wsf + carve(128));
  int*   eprev  = sprev + 32;
  float* m2f    = wsf + carve((size_t)NBS*NH);
  float* b2p[2] = {wsf + carve(NPH2), wsf + carve(NPH2)};
  float* b1p[2] = {wsf + carve(NPH2), wsf + carve(NPH2)};
  float* rbuf   = wsf + carve((size_t)NB*NH);
  float* gsbuf  = wsf + carve((size_t)NB*NG);
  float* lgbuf  = wsf + carve((size_t)NB*NS);
  float* W1rT[2]= {wsf + carve((size_t)NH*NPH), wsf + carve((size_t)NH*NPH)};
  ushort* modExp   = (ushort*)(wsf + carve((size_t)NBS*K1/2));
  ushort* W1exp[2] = {(ushort*)(wsf + carve((size_t)NPH2*K1/2)),
                      (ushort*)(wsf + carve((size_t)NPH2*K1/2))};
  ushort* W2exp[2] = {(ushort*)(wsf + carve((size_t)NPH2*K2/2)),
                      (ushort*)(wsf + carve((size_t)NPH2*K2/2))};
  ushort* m1exp    = (ushort*)(wsf + carve((size_t)NBS*K2/2));

  // ---- init + prep (every launch; deterministic) ----
  init_kernel<<<NB, 256, 0, stream>>>(mask, hbuf, cbuf, sprev, eprev);
  conv_mod_k<<<2048, 256, 0, stream>>>(mod, modExp);
  pad_zero_k<<<256, 256, 0, stream>>>(m1exp, K2, 3*NH, K2-3*NH, NBS);
  for (int net=0; net<2; net++){
    conv_w1_k<<<2048, 256, 0, stream>>>(W1[net], W1exp[net]);
    conv_w2_k<<<1024, 256, 0, stream>>>(W2[net], W2exp[net]);
    conv_w1r_k<<<1024, 256, 0, stream>>>(W1[net], W1rT[net]);
    permv_k<<<(NPH2+255)/256, 256, 0, stream>>>(b2[net], b2p[net]);
    permv_k<<<(NPH2+255)/256, 256, 0, stream>>>(b1[net], b1p[net]);
  }

  dim3 ggrid(NBS/256, NPH2/256);
  for (int t=0; t<NT; t++){
    lstm_gates<<<dim3(NB, NG/4), 256, 0, stream>>>(mod, sprev, eprev, hbuf,
                                                   Wih, Whh, bih, bhh, gsbuf);
    lstm_update<<<NB, 256, 0, stream>>>(gsbuf, hbuf, cbuf);
    for (int net=0; net<2; net++){
      r_kernel<<<dim3(NB, NH/4), 256, 0, stream>>>(mod, sprev, eprev, hbuf, rW[net], rbuf);
      prer_kernel<<<dim3(NB, NPH2/256), 256, 0, stream>>>(rbuf, W1rT[net], b1p[net], prer);
      gemm_fused<0><<<ggrid, 512, 0, stream>>>(modExp, W1exp[net], prer, (void*)m1exp);
      gemm_fused<1><<<ggrid, 512, 0, stream>>>(m1exp, W2exp[net], b2p[net], (void*)m2f);
      logits_main<<<dim3(NB, 2), 256, 0, stream>>>(m1exp, m2f, W3[net], b3[net], mask, lgbuf);
      logits_fin<<<NB, 256, 0, stream>>>(lgbuf, out[net], t, net==0 ? sprev : eprev);
    }
  }
}

// Round 6
// 2725.369 us; speedup vs baseline: 1.6818x; 1.2225x over previous
//
#include <hip/hip_runtime.h>
#include <math.h>

#define NB 32
#define NS 400
#define NM 400
#define NH 200
#define NP 16
#define NT 4
#define NBS (NB*NS)          // 12800
#define NPH (NP*NH)          // 3200
#define NPH2 3328            // padded N (13*256)
#define NJT 13               // NPH2/256
#define NX  (2*NM)           // 800
#define NG  (4*NH)           // 800
#define NR  (2*NM+NH)        // 1000
#define K1  1280             // m1 GEMM K' (3*400 padded)
#define K2  640              // m2 GEMM K' (3*200 padded)

typedef __attribute__((ext_vector_type(8))) short short8v;
typedef __attribute__((ext_vector_type(4))) float f32x4;
typedef __attribute__((ext_vector_type(4))) unsigned short us4;
typedef unsigned short ushort;

__device__ __forceinline__ float sigf(float x){ return 1.0f/(1.0f+expf(-x)); }

__device__ __forceinline__ ushort f2bf(float x){
  union{float f; unsigned u;} v; v.f=x;
  unsigned r = v.u + 0x7fffu + ((v.u>>16)&1u);
  return (ushort)(r>>16);
}
__device__ __forceinline__ float bf2f(ushort u){
  union{float f; unsigned v;} x; x.v = ((unsigned)u)<<16; return x.f;
}
__device__ __forceinline__ float wave_sum(float v){
  #pragma unroll
  for (int o=32;o>0;o>>=1) v += __shfl_xor(v, o);
  return v;
}

// ---------------- init: h=c=0, sprev=0, eprev=sum(mask)-1 ----------------
__global__ __launch_bounds__(256) void init_kernel(const float* __restrict__ mask,
    float* __restrict__ h, float* __restrict__ c,
    int* __restrict__ sprev, int* __restrict__ eprev){
  int b = blockIdx.x, tid = threadIdx.x;
  __shared__ float red[256];
  float s = 0.f;
  for (int i=tid;i<NS;i+=256) s += mask[(size_t)b*NS+i];
  red[tid]=s; __syncthreads();
  for (int st=128;st>0;st>>=1){ if(tid<st) red[tid]+=red[tid+st]; __syncthreads(); }
  if (tid==0){ sprev[b]=0; eprev[b]=(int)red[0]-1; }
  for (int i=tid;i<NH;i+=256){ h[(size_t)b*NH+i]=0.f; c[(size_t)b*NH+i]=0.f; }
}

// ---------------- conversions / prep ----------------
// mod [12800][400] f32 -> modExp [12800][1280] bf16 [hi|lo|hi|0]
__global__ __launch_bounds__(256) void conv_mod_k(const float* __restrict__ in, ushort* __restrict__ out){
  for (size_t i = (size_t)blockIdx.x*256+threadIdx.x; i < (size_t)NBS*K1; i += (size_t)gridDim.x*256){
    int r = (int)(i/K1), k = (int)(i%K1);
    ushort v = 0;
    if (k < 3*NM){
      float x = in[(size_t)r*NM + (k % NM)];
      ushort h = f2bf(x);
      v = (k < NM || k >= 2*NM) ? h : f2bf(x - bf2f(h));
    }
    out[i] = v;
  }
}
// W1 [3200][600] -> W1exp [3328][1280] rows permuted jp=h*16+p, [hi|hi|lo|0]; rows>=3200 zero
__global__ __launch_bounds__(256) void conv_w1_k(const float* __restrict__ in, ushort* __restrict__ out){
  for (size_t i = (size_t)blockIdx.x*256+threadIdx.x; i < (size_t)NPH2*K1; i += (size_t)gridDim.x*256){
    int jp = (int)(i/K1), k = (int)(i%K1);
    ushort v = 0;
    if (jp < NPH && k < 3*NM){
      int j = (jp&15)*NH + (jp>>4);
      float x = in[(size_t)j*(NM+NH) + (k % NM)];
      ushort h = f2bf(x);
      v = (k < 2*NM) ? h : f2bf(x - bf2f(h));
    }
    out[i] = v;
  }
}
// W2 [3200][200] -> W2exp [3328][640]
__global__ __launch_bounds__(256) void conv_w2_k(const float* __restrict__ in, ushort* __restrict__ out){
  for (size_t i = (size_t)blockIdx.x*256+threadIdx.x; i < (size_t)NPH2*K2; i += (size_t)gridDim.x*256){
    int jp = (int)(i/K2), k = (int)(i%K2);
    ushort v = 0;
    if (jp < NPH && k < 3*NH){
      int j = (jp&15)*NH + (jp>>4);
      float x = in[(size_t)j*NH + (k % NH)];
      ushort h = f2bf(x);
      v = (k < 2*NH) ? h : f2bf(x - bf2f(h));
    }
    out[i] = v;
  }
}
// W1rT[k][jp] = W1[j][400+k], jp-permuted; k<200, jp<3200
__global__ __launch_bounds__(256) void conv_w1r_k(const float* __restrict__ in, float* __restrict__ out){
  for (size_t i = (size_t)blockIdx.x*256+threadIdx.x; i < (size_t)NH*NPH; i += (size_t)gridDim.x*256){
    int k = (int)(i/NPH), jp = (int)(i%NPH);
    int hh = jp>>4, p = jp&15, j = p*NH + hh;
    out[i] = in[(size_t)j*(NM+NH) + NM + k];
  }
}
// permute bias vector into jp order, pad to NPH2 with zeros
__global__ __launch_bounds__(256) void permv_k(const float* __restrict__ in, float* __restrict__ out){
  int i = blockIdx.x*256+threadIdx.x;
  if (i < NPH) out[(i%NH)*NP + i/NH] = in[i];
  else if (i < NPH2) out[i] = 0.f;
}
__global__ __launch_bounds__(256) void pad_zero_k(ushort* __restrict__ p, int stride, int start, int width, int rows){
  for (size_t i = (size_t)blockIdx.x*256+threadIdx.x; i < (size_t)rows*width; i += (size_t)gridDim.x*256){
    int r = (int)(i/width), j = (int)(i%width);
    p[(size_t)r*stride + start + j] = 0;
  }
}

// ---------------- LSTM gates (wave per gate) ----------------
__global__ __launch_bounds__(256) void lstm_gates(const float* __restrict__ mod,
    const int* __restrict__ sprev, const int* __restrict__ eprev,
    const float* __restrict__ h,
    const float* __restrict__ Wih, const float* __restrict__ Whh,
    const float* __restrict__ bih, const float* __restrict__ bhh,
    float* __restrict__ gs){
  int b=blockIdx.x, tid=threadIdx.x;
  __shared__ float xs[NX+NH];
  const float* us = mod + ((size_t)b*NS + sprev[b])*NM;
  const float* ue = mod + ((size_t)b*NS + eprev[b])*NM;
  for (int i=tid;i<NM;i+=256){ xs[i]=us[i]; xs[NM+i]=ue[i]; }
  for (int i=tid;i<NH;i+=256) xs[NX+i]=h[(size_t)b*NH+i];
  __syncthreads();
  int w=tid>>6, lane=tid&63;
  int j = blockIdx.y*4 + w;                 // gridDim.y = 200 -> j < 800
  const float* wih = Wih + (size_t)j*NX;
  const float* whh = Whh + (size_t)j*NH;
  float acc=0.f;
  for (int k=lane;k<NX;k+=64) acc += xs[k]*wih[k];
  for (int k=lane;k<NH;k+=64) acc += xs[NX+k]*whh[k];
  acc = wave_sum(acc);
  if (lane==0) gs[(size_t)b*NG+j] = acc + bih[j] + bhh[j];
}
__global__ __launch_bounds__(256) void lstm_update(const float* __restrict__ gs,
    float* __restrict__ h, float* __restrict__ c){
  int b=blockIdx.x, j=threadIdx.x;
  if (j<NH){
    float iv=gs[(size_t)b*NG+j], fv=gs[(size_t)b*NG+NH+j];
    float gv=gs[(size_t)b*NG+2*NH+j], ov=gs[(size_t)b*NG+3*NH+j];
    float c2 = sigf(fv)*c[(size_t)b*NH+j] + sigf(iv)*tanhf(gv);
    c[(size_t)b*NH+j]=c2;
    h[(size_t)b*NH+j]=sigf(ov)*tanhf(c2);
  }
}

// ---------------- r = tanh([h,us,ue]@rW^T), wave per output ----------------
__global__ __launch_bounds__(256) void r_kernel(const float* __restrict__ mod,
    const int* __restrict__ sprev, const int* __restrict__ eprev,
    const float* __restrict__ h, const float* __restrict__ rW,
    float* __restrict__ rbuf){
  int b=blockIdx.x, tid=threadIdx.x;
  __shared__ float zs[NR];
  const float* us = mod + ((size_t)b*NS + sprev[b])*NM;
  const float* ue = mod + ((size_t)b*NS + eprev[b])*NM;
  for (int i=tid;i<NH;i+=256) zs[i]=h[(size_t)b*NH+i];
  for (int i=tid;i<NM;i+=256){ zs[NH+i]=us[i]; zs[NH+NM+i]=ue[i]; }
  __syncthreads();
  int w=tid>>6, lane=tid&63;
  int j = blockIdx.y*4 + w;                 // gridDim.y = 50 -> j < 200
  const float* wr = rW + (size_t)j*NR;
  float acc=0.f;
  for (int k=lane;k<NR;k+=64) acc += zs[k]*wr[k];
  acc = wave_sum(acc);
  if (lane==0) rbuf[(size_t)b*NH+j] = tanhf(acc);
}

// ---------------- prer[b][jp] = b1p[jp] + sum_k r[b][k]*W1rT[k][jp]; padded N ----------------
__global__ __launch_bounds__(256) void prer_kernel(const float* __restrict__ rbuf,
    const float* __restrict__ W1rT, const float* __restrict__ b1p,
    float* __restrict__ prer){
  int b=blockIdx.x, tid=threadIdx.x;
  __shared__ float rs[NH];
  if (tid < NH) rs[tid] = rbuf[(size_t)b*NH+tid];
  __syncthreads();
  int jp = blockIdx.y*256 + tid;
  if (jp < NPH2){
    float acc = 0.f;
    if (jp < NPH){
      acc = b1p[jp];
      #pragma unroll 8
      for (int k=0;k<NH;k++) acc += rs[k]*W1rT[(size_t)k*NPH + jp];
    }
    prer[(size_t)b*NPH2 + jp] = acc;
  }
}

// ------------- fused bf16-split GEMM, 256x256 tile, BK=32, 4-slot 3-deep pipeline -------------
// MODE 0: bias=prer per-b, out = m1exp ushort[12800][640] (bias+max-over-p epilogue)
// MODE 1: bias=b2p uniform, out = m2f float[12800][200]   (bias+max-over-p epilogue)
// MODE 2: no bias, out = premod float[12800][3200] raw accumulators
// Work order: XCD-chunked (bijective), i-major j-fast for L2 A-panel reuse.
template<int MODE>
__global__ __launch_bounds__(512, 2) void gemm_fused(
    const ushort* __restrict__ A, const ushort* __restrict__ W,
    const float* __restrict__ bias, void* __restrict__ outp){
  constexpr int LDK = (MODE==1) ? K2 : K1;
  constexpr int NTI = LDK/32;
  __shared__ __align__(16) ushort As[4][256*32];
  __shared__ __align__(16) ushort Bs[4][256*32];
  __shared__ float biasLds[2][256];
  __shared__ float outT[256][16];
  const int tid = threadIdx.x;
  // bijective XCD-chunked swizzle (nwg=650): xcd k gets contiguous work chunk
  const int nwg = gridDim.x;
  const int q = nwg >> 3, r = nwg & 7;
  const int xcd = blockIdx.x & 7, sub = blockIdx.x >> 3;
  const int wkid = (xcd < r) ? (xcd*(q+1) + sub) : (r*(q+1) + (xcd-r)*q + sub);
  const int i0 = (wkid / NJT) * 256, j0 = (wkid % NJT) * 256;
  const int b0 = i0/NS;
  if (MODE==0){
    if (tid<256) biasLds[0][tid] = bias[(size_t)b0*NPH2 + j0 + tid];
    else { int b1r=(i0+255)/NS; biasLds[1][tid-256] = bias[(size_t)b1r*NPH2 + j0 + (tid-256)]; }
  } else if (MODE==1){
    if (tid<256) biasLds[0][tid] = bias[j0+tid];
  }
  const int w = tid>>6, l = tid&63;
  const int wr = w>>2, wc = w&3;            // 2M x 4N waves, wave tile 128x64
  const int fr = l&15, fk = l>>4;
  // staging: wave w stages rows [w*32, w*32+32) of both A and B; 2 insts each.
  // LDS[row][cu] = G[row][kt*32 + (cu ^ ((row&3)<<3))]  (cu = ushort col in [0,32))
  const int srow = w*32 + (l>>2);
  const int sslot = l&3;
  const int swzc = (sslot ^ (srow&3))*8;    // ushort units; (srow+16)&3 == srow&3
  const ushort* gA0 = A + (size_t)(i0+srow)*LDK + swzc;
  const ushort* gB0 = W + (size_t)(j0+srow)*LDK + swzc;
  const int ldsOff = srow*32 + sslot*8;     // == w*1024 + l*8 : linear in lane
  auto stage = [&](int slot, int kt){
    const ushort* a = gA0 + kt*32;
    const ushort* b = gB0 + kt*32;
    __builtin_amdgcn_global_load_lds((const __attribute__((address_space(1))) void*)a,
        (__attribute__((address_space(3))) void*)(&As[slot][ldsOff]), 16, 0, 0);
    __builtin_amdgcn_global_load_lds((const __attribute__((address_space(1))) void*)(a + 16*LDK),
        (__attribute__((address_space(3))) void*)(&As[slot][ldsOff + 16*32]), 16, 0, 0);
    __builtin_amdgcn_global_load_lds((const __attribute__((address_space(1))) void*)b,
        (__attribute__((address_space(3))) void*)(&Bs[slot][ldsOff]), 16, 0, 0);
    __builtin_amdgcn_global_load_lds((const __attribute__((address_space(1))) void*)(b + 16*LDK),
        (__attribute__((address_space(3))) void*)(&Bs[slot][ldsOff + 16*32]), 16, 0, 0);
  };
  f32x4 acc[8][4] = {};
  stage(0,0); stage(1,1); stage(2,2);
  for (int t=0; t<NTI; t++){
    // tile t landed (4 loads/wave/tile; t+1,t+2 may stay in flight), collective barrier
    if (t+2 < NTI)      asm volatile("s_waitcnt vmcnt(8)\n\ts_barrier" ::: "memory");
    else if (t+1 < NTI) asm volatile("s_waitcnt vmcnt(4)\n\ts_barrier" ::: "memory");
    else                asm volatile("s_waitcnt vmcnt(0)\n\ts_barrier" ::: "memory");
    const int s = t&3;
    short8v a[8], b[4];
    #pragma unroll
    for (int m=0;m<8;m++){
      int row = wr*128 + m*16 + fr;
      a[m] = *(const short8v*)&As[s][row*32 + ((fk ^ (row&3))*8)];
    }
    #pragma unroll
    for (int n=0;n<4;n++){
      int row = wc*64 + n*16 + fr;
      b[n] = *(const short8v*)&Bs[s][row*32 + ((fk ^ (row&3))*8)];
    }
    // prefetch tile t+3 into slot (t+3)&3 == (t-1)&3 : its reads retired before this
    // iteration's barrier (consumed by iter t-1 MFMAs), so WAR-safe.
    if (t+3 < NTI) stage((t+3)&3, t+3);
    __builtin_amdgcn_s_setprio(1);
    #pragma unroll
    for (int m=0;m<8;m++)
      #pragma unroll
      for (int n=0;n<4;n++)
        acc[m][n] = __builtin_amdgcn_mfma_f32_16x16x32_bf16(a[m], b[n], acc[m][n], 0,0,0);
    __builtin_amdgcn_s_setprio(0);
  }
  if (MODE==2){
    float* o = (float*)outp;
    #pragma unroll
    for (int m=0;m<8;m++){
      #pragma unroll
      for (int n=0;n<4;n++){
        int col = j0 + wc*64 + n*16 + fr;
        if (col < NPH){
          int rbase = i0 + wr*128 + m*16 + fk*4;
          #pragma unroll
          for (int reg=0;reg<4;reg++)
            o[(size_t)(rbase+reg)*NPH + col] = acc[m][n][reg];
        }
      }
    }
    return;
  }
  __syncthreads();
  // epilogue: bias + max over the 16 cols (=p) of each 16x16 fragment
  const int blim = (b0+1)*NS;
  #pragma unroll
  for (int m=0;m<8;m++){
    #pragma unroll
    for (int n=0;n<4;n++){
      int colL = wc*64 + n*16 + fr;
      int rbase = wr*128 + m*16 + fk*4;
      #pragma unroll
      for (int reg=0; reg<4; reg++){
        int rowL = rbase + reg;
        float bv = (MODE==0 && (i0+rowL) >= blim) ? biasLds[1][colL] : biasLds[0][colL];
        float v = acc[m][n][reg] + bv;
        v = fmaxf(v, __shfl_xor(v,1));
        v = fmaxf(v, __shfl_xor(v,2));
        v = fmaxf(v, __shfl_xor(v,4));
        v = fmaxf(v, __shfl_xor(v,8));
        if (fr==0) outT[rowL][wc*4+n] = v;
      }
    }
  }
  __syncthreads();
  {
    int rowL = tid>>1;
    int hloc0 = (tid&1)*8;
    int hg0 = (j0>>4) + hloc0;
    if (hg0 < NH){
      int absrow = i0 + rowL;
      float v[8];
      #pragma unroll
      for (int qq=0;qq<8;qq++) v[qq] = outT[rowL][hloc0+qq];
      if (MODE==0){
        ushort* o = (ushort*)outp + (size_t)absrow*K2 + hg0;
        ushort hi[8], lo[8];
        #pragma unroll
        for (int qq=0;qq<8;qq++){ hi[qq]=f2bf(v[qq]); lo[qq]=f2bf(v[qq]-bf2f(hi[qq])); }
        *(us4*)(o)        = (us4){hi[0],hi[1],hi[2],hi[3]};
        *(us4*)(o+4)      = (us4){hi[4],hi[5],hi[6],hi[7]};
        *(us4*)(o+NH)     = (us4){lo[0],lo[1],lo[2],lo[3]};
        *(us4*)(o+NH+4)   = (us4){lo[4],lo[5],lo[6],lo[7]};
        *(us4*)(o+2*NH)   = (us4){hi[0],hi[1],hi[2],hi[3]};
        *(us4*)(o+2*NH+4) = (us4){hi[4],hi[5],hi[6],hi[7]};
      } else {
        float* o = (float*)outp + (size_t)absrow*NH + hg0;
        *(f32x4*)o     = (f32x4){v[0],v[1],v[2],v[3]};
        *(f32x4*)(o+4) = (f32x4){v[4],v[5],v[6],v[7]};
      }
    }
  }
}

// --------- hoisted m1: m1[i][h] = max_p(premod[i][h*16+p] + prer[b][h*16+p]) ---------
__global__ __launch_bounds__(256) void maxp_kernel(const float* __restrict__ premod,
    const float* __restrict__ prer, ushort* __restrict__ m1e){
  int i = blockIdx.x;
  int b = i / NS;
  int h = threadIdx.x;
  if (h >= NH) return;
  const float* pm = premod + (size_t)i*NPH + h*16;
  const float* pr = prer + (size_t)b*NPH2 + h*16;
  float v = -INFINITY;
  #pragma unroll
  for (int p=0;p<16;p+=4){
    f32x4 a = *(const f32x4*)(pm+p);
    f32x4 c = *(const f32x4*)(pr+p);
    v = fmaxf(v, fmaxf(fmaxf(a.x+c.x, a.y+c.y), fmaxf(a.z+c.z, a.w+c.w)));
  }
  ushort hi = f2bf(v), lo = f2bf(v - bf2f(hi));
  ushort* o = m1e + (size_t)i*K2;
  o[h] = hi; o[NH+h] = lo; o[2*NH+h] = hi;
}

// --------- logits main: one thread per s, grid (NB, 2) ---------
__global__ __launch_bounds__(256) void logits_main(const ushort* __restrict__ m1e,
    const float* __restrict__ m2, const float* __restrict__ W3, const float* __restrict__ b3,
    const float* __restrict__ mask, float* __restrict__ lg){
  int b=blockIdx.x;
  int s=blockIdx.y*256+threadIdx.x;
  if (s >= NS) return;
  const ushort* a = m1e + (size_t)(b*NS+s)*K2;
  const float4* d = (const float4*)(m2 + (size_t)(b*NS+s)*NH);
  float acc[NP];
  #pragma unroll
  for (int p=0;p<NP;p++) acc[p]=b3[p];
  for (int k=0;k<NH/4;k++){
    us4 hv = *(const us4*)(a + 4*k);
    us4 lv = *(const us4*)(a + NH + 4*k);
    float4 dv = d[k];
    float a0=bf2f(hv.x)+bf2f(lv.x), a1=bf2f(hv.y)+bf2f(lv.y);
    float a2=bf2f(hv.z)+bf2f(lv.z), a3=bf2f(hv.w)+bf2f(lv.w);
    #pragma unroll
    for (int p=0;p<NP;p++){
      const float* wp = W3 + p*(2*NH) + 4*k;        // wave-uniform -> s_load
      acc[p] += a0*wp[0]+a1*wp[1]+a2*wp[2]+a3*wp[3];
      const float* w2 = wp + NH;
      acc[p] += dv.x*w2[0]+dv.y*w2[1]+dv.z*w2[2]+dv.w*w2[3];
    }
  }
  float best=acc[0];
  #pragma unroll
  for (int p=1;p<NP;p++) best=fmaxf(best,acc[p]);
  lg[(size_t)b*NS+s] = (mask[(size_t)b*NS+s] > 0.f) ? best : -1e30f;
}

// --------- logits finish: log_softmax + argmax; one block per b ---------
__global__ __launch_bounds__(256) void logits_fin(const float* __restrict__ lg,
    float* __restrict__ out, int t, int* __restrict__ prevIdx){
  int b=blockIdx.x, tid=threadIdx.x;
  __shared__ float rv[256]; __shared__ int ri[256]; __shared__ float sv[256];
  float bv=-INFINITY; int bi=NS;
  for (int s=tid;s<NS;s+=256){ float v=lg[(size_t)b*NS+s]; if (v>bv){bv=v;bi=s;} }
  rv[tid]=bv; ri[tid]=bi; __syncthreads();
  for (int st=128;st>0;st>>=1){
    if (tid<st){
      float v2=rv[tid+st]; int i2=ri[tid+st];
      if (v2>rv[tid] || (v2==rv[tid] && i2<ri[tid])){ rv[tid]=v2; ri[tid]=i2; }
    }
    __syncthreads();
  }
  float mx = rv[0];
  float ps=0.f;
  for (int s=tid;s<NS;s+=256) ps += expf(lg[(size_t)b*NS+s]-mx);
  sv[tid]=ps; __syncthreads();
  for (int st=128;st>0;st>>=1){ if (tid<st) sv[tid]+=sv[tid+st]; __syncthreads(); }
  float lse = mx + logf(sv[0]);
  for (int s=tid;s<NS;s+=256) out[((size_t)b*NT + t)*NS + s] = lg[(size_t)b*NS+s]-lse;
  if (tid==0) prevIdx[b]=ri[0];
}

// =============================== host ===============================
extern "C" void kernel_launch(void* const* d_in, const int* in_sizes, int n_in,
                              void* d_out, int out_size, void* d_ws, size_t ws_size,
                              hipStream_t stream){
  const float* mod  = (const float*)d_in[1];
  const float* mask = (const float*)d_in[2];
  const float* Wih  = (const float*)d_in[3];
  const float* Whh  = (const float*)d_in[4];
  const float* bih  = (const float*)d_in[5];
  const float* bhh  = (const float*)d_in[6];
  const float* rW[2] = {(const float*)d_in[7],  (const float*)d_in[14]};
  const float* W1[2] = {(const float*)d_in[8],  (const float*)d_in[15]};
  const float* b1[2] = {(const float*)d_in[9],  (const float*)d_in[16]};
  const float* W2[2] = {(const float*)d_in[10], (const float*)d_in[17]};
  const float* b2[2] = {(const float*)d_in[11], (const float*)d_in[18]};
  const float* W3[2] = {(const float*)d_in[12], (const float*)d_in[19]};
  const float* b3[2] = {(const float*)d_in[13], (const float*)d_in[20]};
  float* out[2];
  out[0] = (float*)d_out;
  out[1] = out[0] + (size_t)NB*NT*NS;

  float* wsf = (float*)d_ws;
  size_t off = 0;
  auto carve = [&](size_t n)->size_t{ size_t o=off; off += (n + 63) & ~(size_t)63; return o; };
  float* hbuf   = wsf + carve((size_t)NB*NH);
  float* cbuf   = wsf + carve((size_t)NB*NH);
  float* prer   = wsf + carve((size_t)NB*NPH2);
  int*   sprev  = (int*)(wsf + carve(128));
  int*   eprev  = sprev + 32;
  float* m2f    = wsf + carve((size_t)NBS*NH);
  float* b2p[2] = {wsf + carve(NPH2), wsf + carve(NPH2)};
  float* b1p[2] = {wsf + carve(NPH2), wsf + carve(NPH2)};
  float* rbuf   = wsf + carve((size_t)NB*NH);
  float* gsbuf  = wsf + carve((size_t)NB*NG);
  float* lgbuf  = wsf + carve((size_t)NB*NS);
  float* W1rT[2]= {wsf + carve((size_t)NH*NPH), wsf + carve((size_t)NH*NPH)};
  ushort* modExp   = (ushort*)(wsf + carve((size_t)NBS*K1/2));
  ushort* W1exp[2] = {(ushort*)(wsf + carve((size_t)NPH2*K1/2)),
                      (ushort*)(wsf + carve((size_t)NPH2*K1/2))};
  ushort* W2exp[2] = {(ushort*)(wsf + carve((size_t)NPH2*K2/2)),
                      (ushort*)(wsf + carve((size_t)NPH2*K2/2))};
  ushort* m1exp    = (ushort*)(wsf + carve((size_t)NBS*K2/2));

  // ---- hoisted premod buffers if workspace allows (per-net fallback otherwise) ----
  const size_t premodN = (size_t)NBS * NPH;       // 40.96M floats = 163.8 MB
  size_t availF = ws_size / 4;
  int nHoist = 0;
  float* premod[2] = {nullptr, nullptr};
  if (availF >= off + 2*premodN + 128){
    nHoist = 2; premod[0] = wsf + carve(premodN); premod[1] = wsf + carve(premodN);
  } else if (availF >= off + premodN + 128){
    nHoist = 1; premod[0] = wsf + carve(premodN);
  }

  // ---- init + prep (every launch; deterministic) ----
  init_kernel<<<NB, 256, 0, stream>>>(mask, hbuf, cbuf, sprev, eprev);
  conv_mod_k<<<2048, 256, 0, stream>>>(mod, modExp);
  pad_zero_k<<<256, 256, 0, stream>>>(m1exp, K2, 3*NH, K2-3*NH, NBS);
  for (int net=0; net<2; net++){
    conv_w1_k<<<2048, 256, 0, stream>>>(W1[net], W1exp[net]);
    conv_w2_k<<<1024, 256, 0, stream>>>(W2[net], W2exp[net]);
    conv_w1r_k<<<1024, 256, 0, stream>>>(W1[net], W1rT[net]);
    permv_k<<<(NPH2+255)/256, 256, 0, stream>>>(b2[net], b2p[net]);
    permv_k<<<(NPH2+255)/256, 256, 0, stream>>>(b1[net], b1p[net]);
  }
  for (int net=0; net<nHoist; net++)
    gemm_fused<2><<<NBS/256*NJT, 512, 0, stream>>>(modExp, W1exp[net], nullptr, (void*)premod[net]);

  for (int t=0; t<NT; t++){
    lstm_gates<<<dim3(NB, NG/4), 256, 0, stream>>>(mod, sprev, eprev, hbuf,
                                                   Wih, Whh, bih, bhh, gsbuf);
    lstm_update<<<NB, 256, 0, stream>>>(gsbuf, hbuf, cbuf);
    for (int net=0; net<2; net++){
      r_kernel<<<dim3(NB, NH/4), 256, 0, stream>>>(mod, sprev, eprev, hbuf, rW[net], rbuf);
      prer_kernel<<<dim3(NB, NPH2/256), 256, 0, stream>>>(rbuf, W1rT[net], b1p[net], prer);
      if (net < nHoist)
        maxp_kernel<<<NBS, 256, 0, stream>>>(premod[net], prer, m1exp);
      else
        gemm_fused<0><<<NBS/256*NJT, 512, 0, stream>>>(modExp, W1exp[net], prer, (void*)m1exp);
      gemm_fused<1><<<NBS/256*NJT, 512, 0, stream>>>(m1exp, W2exp[net], b2p[net], (void*)m2f);
      logits_main<<<dim3(NB, 2), 256, 0, stream>>>(m1exp, m2f, W3[net], b3[net], mask, lgbuf);
      logits_fin<<<NB, 256, 0, stream>>>(lgbuf, out[net], t, net==0 ? sprev : eprev);
    }
  }
}

// Round 7
// 2670.816 us; speedup vs baseline: 1.7162x; 1.0204x over previous
//
#include <hip/hip_runtime.h>
#include <math.h>

#define NB 32
#define NS 400
#define NM 400
#define NH 200
#define NP 16
#define NT 4
#define NBS (NB*NS)          // 12800
#define NPH (NP*NH)          // 3200
#define NPH2 3328            // padded N (13*256)
#define NJT 13               // NPH2/256
#define NX  (2*NM)           // 800
#define NG  (4*NH)           // 800
#define NR  (2*NM+NH)        // 1000
#define K1  1280             // m1 GEMM K' (3*400 padded)
#define K2  640              // m2 GEMM K' (3*200 padded)

typedef __attribute__((ext_vector_type(8))) short short8v;
typedef __attribute__((ext_vector_type(4))) float f32x4;
typedef __attribute__((ext_vector_type(4))) unsigned short us4;
typedef unsigned short ushort;

__device__ __forceinline__ float sigf(float x){ return 1.0f/(1.0f+expf(-x)); }

__device__ __forceinline__ ushort f2bf(float x){
  union{float f; unsigned u;} v; v.f=x;
  unsigned r = v.u + 0x7fffu + ((v.u>>16)&1u);
  return (ushort)(r>>16);
}
__device__ __forceinline__ float bf2f(ushort u){
  union{float f; unsigned v;} x; x.v = ((unsigned)u)<<16; return x.f;
}
__device__ __forceinline__ float wave_sum(float v){
  #pragma unroll
  for (int o=32;o>0;o>>=1) v += __shfl_xor(v, o);
  return v;
}

// ---------------- init: h=c=0, sprev=0, eprev=sum(mask)-1 ----------------
__global__ __launch_bounds__(256) void init_kernel(const float* __restrict__ mask,
    float* __restrict__ h, float* __restrict__ c,
    int* __restrict__ sprev, int* __restrict__ eprev){
  int b = blockIdx.x, tid = threadIdx.x;
  __shared__ float red[256];
  float s = 0.f;
  for (int i=tid;i<NS;i+=256) s += mask[(size_t)b*NS+i];
  red[tid]=s; __syncthreads();
  for (int st=128;st>0;st>>=1){ if(tid<st) red[tid]+=red[tid+st]; __syncthreads(); }
  if (tid==0){ sprev[b]=0; eprev[b]=(int)red[0]-1; }
  for (int i=tid;i<NH;i+=256){ h[(size_t)b*NH+i]=0.f; c[(size_t)b*NH+i]=0.f; }
}

// ---------------- conversions / prep ----------------
// mod [12800][400] f32 -> modExp [12800][1280] bf16 [hi|lo|hi|0]
__global__ __launch_bounds__(256) void conv_mod_k(const float* __restrict__ in, ushort* __restrict__ out){
  for (size_t i = (size_t)blockIdx.x*256+threadIdx.x; i < (size_t)NBS*K1; i += (size_t)gridDim.x*256){
    int r = (int)(i/K1), k = (int)(i%K1);
    ushort v = 0;
    if (k < 3*NM){
      float x = in[(size_t)r*NM + (k % NM)];
      ushort h = f2bf(x);
      v = (k < NM || k >= 2*NM) ? h : f2bf(x - bf2f(h));
    }
    out[i] = v;
  }
}
// W1 [3200][600] -> W1exp [3328][1280] rows permuted jp=h*16+p, [hi|hi|lo|0]; rows>=3200 zero
__global__ __launch_bounds__(256) void conv_w1_k(const float* __restrict__ in, ushort* __restrict__ out){
  for (size_t i = (size_t)blockIdx.x*256+threadIdx.x; i < (size_t)NPH2*K1; i += (size_t)gridDim.x*256){
    int jp = (int)(i/K1), k = (int)(i%K1);
    ushort v = 0;
    if (jp < NPH && k < 3*NM){
      int j = (jp&15)*NH + (jp>>4);
      float x = in[(size_t)j*(NM+NH) + (k % NM)];
      ushort h = f2bf(x);
      v = (k < 2*NM) ? h : f2bf(x - bf2f(h));
    }
    out[i] = v;
  }
}
// W2 [3200][200] -> W2exp [3328][640]
__global__ __launch_bounds__(256) void conv_w2_k(const float* __restrict__ in, ushort* __restrict__ out){
  for (size_t i = (size_t)blockIdx.x*256+threadIdx.x; i < (size_t)NPH2*K2; i += (size_t)gridDim.x*256){
    int jp = (int)(i/K2), k = (int)(i%K2);
    ushort v = 0;
    if (jp < NPH && k < 3*NH){
      int j = (jp&15)*NH + (jp>>4);
      float x = in[(size_t)j*NH + (k % NH)];
      ushort h = f2bf(x);
      v = (k < 2*NH) ? h : f2bf(x - bf2f(h));
    }
    out[i] = v;
  }
}
// W1rT[k][jp] = W1[j][400+k], jp-permuted; k<200, jp<3200
__global__ __launch_bounds__(256) void conv_w1r_k(const float* __restrict__ in, float* __restrict__ out){
  for (size_t i = (size_t)blockIdx.x*256+threadIdx.x; i < (size_t)NH*NPH; i += (size_t)gridDim.x*256){
    int k = (int)(i/NPH), jp = (int)(i%NPH);
    int hh = jp>>4, p = jp&15, j = p*NH + hh;
    out[i] = in[(size_t)j*(NM+NH) + NM + k];
  }
}
// permute bias vector into jp order, pad to NPH2 with zeros
__global__ __launch_bounds__(256) void permv_k(const float* __restrict__ in, float* __restrict__ out){
  int i = blockIdx.x*256+threadIdx.x;
  if (i < NPH) out[(i%NH)*NP + i/NH] = in[i];
  else if (i < NPH2) out[i] = 0.f;
}
__global__ __launch_bounds__(256) void pad_zero_k(ushort* __restrict__ p, int stride, int start, int width, int rows){
  for (size_t i = (size_t)blockIdx.x*256+threadIdx.x; i < (size_t)rows*width; i += (size_t)gridDim.x*256){
    int r = (int)(i/width), j = (int)(i%width);
    p[(size_t)r*stride + start + j] = 0;
  }
}

// ---------------- LSTM gates (wave per gate) ----------------
__global__ __launch_bounds__(256) void lstm_gates(const float* __restrict__ mod,
    const int* __restrict__ sprev, const int* __restrict__ eprev,
    const float* __restrict__ h,
    const float* __restrict__ Wih, const float* __restrict__ Whh,
    const float* __restrict__ bih, const float* __restrict__ bhh,
    float* __restrict__ gs){
  int b=blockIdx.x, tid=threadIdx.x;
  __shared__ float xs[NX+NH];
  const float* us = mod + ((size_t)b*NS + sprev[b])*NM;
  const float* ue = mod + ((size_t)b*NS + eprev[b])*NM;
  for (int i=tid;i<NM;i+=256){ xs[i]=us[i]; xs[NM+i]=ue[i]; }
  for (int i=tid;i<NH;i+=256) xs[NX+i]=h[(size_t)b*NH+i];
  __syncthreads();
  int w=tid>>6, lane=tid&63;
  int j = blockIdx.y*4 + w;                 // gridDim.y = 200 -> j < 800
  const float* wih = Wih + (size_t)j*NX;
  const float* whh = Whh + (size_t)j*NH;
  float acc=0.f;
  for (int k=lane;k<NX;k+=64) acc += xs[k]*wih[k];
  for (int k=lane;k<NH;k+=64) acc += xs[NX+k]*whh[k];
  acc = wave_sum(acc);
  if (lane==0) gs[(size_t)b*NG+j] = acc + bih[j] + bhh[j];
}
__global__ __launch_bounds__(256) void lstm_update(const float* __restrict__ gs,
    float* __restrict__ h, float* __restrict__ c){
  int b=blockIdx.x, j=threadIdx.x;
  if (j<NH){
    float iv=gs[(size_t)b*NG+j], fv=gs[(size_t)b*NG+NH+j];
    float gv=gs[(size_t)b*NG+2*NH+j], ov=gs[(size_t)b*NG+3*NH+j];
    float c2 = sigf(fv)*c[(size_t)b*NH+j] + sigf(iv)*tanhf(gv);
    c[(size_t)b*NH+j]=c2;
    h[(size_t)b*NH+j]=sigf(ov)*tanhf(c2);
  }
}

// ---------------- r = tanh([h,us,ue]@rW^T), wave per output ----------------
__global__ __launch_bounds__(256) void r_kernel(const float* __restrict__ mod,
    const int* __restrict__ sprev, const int* __restrict__ eprev,
    const float* __restrict__ h, const float* __restrict__ rW,
    float* __restrict__ rbuf){
  int b=blockIdx.x, tid=threadIdx.x;
  __shared__ float zs[NR];
  const float* us = mod + ((size_t)b*NS + sprev[b])*NM;
  const float* ue = mod + ((size_t)b*NS + eprev[b])*NM;
  for (int i=tid;i<NH;i+=256) zs[i]=h[(size_t)b*NH+i];
  for (int i=tid;i<NM;i+=256){ zs[NH+i]=us[i]; zs[NH+NM+i]=ue[i]; }
  __syncthreads();
  int w=tid>>6, lane=tid&63;
  int j = blockIdx.y*4 + w;                 // gridDim.y = 50 -> j < 200
  const float* wr = rW + (size_t)j*NR;
  float acc=0.f;
  for (int k=lane;k<NR;k+=64) acc += zs[k]*wr[k];
  acc = wave_sum(acc);
  if (lane==0) rbuf[(size_t)b*NH+j] = tanhf(acc);
}

// ---------------- prer[b][jp] = b1p[jp] + sum_k r[b][k]*W1rT[k][jp]; padded N ----------------
__global__ __launch_bounds__(256) void prer_kernel(const float* __restrict__ rbuf,
    const float* __restrict__ W1rT, const float* __restrict__ b1p,
    float* __restrict__ prer){
  int b=blockIdx.x, tid=threadIdx.x;
  __shared__ float rs[NH];
  if (tid < NH) rs[tid] = rbuf[(size_t)b*NH+tid];
  __syncthreads();
  int jp = blockIdx.y*256 + tid;
  if (jp < NPH2){
    float acc = 0.f;
    if (jp < NPH){
      acc = b1p[jp];
      #pragma unroll 8
      for (int k=0;k<NH;k++) acc += rs[k]*W1rT[(size_t)k*NPH + jp];
    }
    prer[(size_t)b*NPH2 + jp] = acc;
  }
}

// ------------- fused bf16-split GEMM, 256x256 tile, BK=32, 4-slot 3-deep pipeline -------------
// MODE 0: bias=prer per-b, out = m1exp ushort[12800][640] (bias+max-over-p epilogue)
// MODE 1: bias=b2p uniform, out = m2f float[12800][200]   (bias+max-over-p epilogue)
// MODE 2: no bias, out = premod float[12800][3200] raw accumulators
// Work order: XCD-chunked (bijective), i-major j-fast for L2 A-panel reuse.
// LDS swizzle: 64B rows (4x16B slots); LDS[row][slot] holds global slot (slot ^ ((row>>1)&3)).
// Read slot = fk ^ ((row>>1)&3): same-parity rows spread 4 slots x 2 rows = 2-way (free).
template<int MODE>
__global__ __launch_bounds__(512, 2) void gemm_fused(
    const ushort* __restrict__ A, const ushort* __restrict__ W,
    const float* __restrict__ bias, void* __restrict__ outp){
  constexpr int LDK = (MODE==1) ? K2 : K1;
  constexpr int NTI = LDK/32;
  __shared__ __align__(16) ushort As[4][256*32];
  __shared__ __align__(16) ushort Bs[4][256*32];
  __shared__ float biasLds[2][256];
  __shared__ float outT[256][16];
  const int tid = threadIdx.x;
  // bijective XCD-chunked swizzle (nwg=650): xcd k gets contiguous work chunk
  const int nwg = gridDim.x;
  const int q = nwg >> 3, r = nwg & 7;
  const int xcd = blockIdx.x & 7, sub = blockIdx.x >> 3;
  const int wkid = (xcd < r) ? (xcd*(q+1) + sub) : (r*(q+1) + (xcd-r)*q + sub);
  const int i0 = (wkid / NJT) * 256, j0 = (wkid % NJT) * 256;
  const int b0 = i0/NS;
  if (MODE==0){
    if (tid<256) biasLds[0][tid] = bias[(size_t)b0*NPH2 + j0 + tid];
    else { int b1r=(i0+255)/NS; biasLds[1][tid-256] = bias[(size_t)b1r*NPH2 + j0 + (tid-256)]; }
  } else if (MODE==1){
    if (tid<256) biasLds[0][tid] = bias[j0+tid];
  }
  const int w = tid>>6, l = tid&63;
  const int wr = w>>2, wc = w&3;            // 2M x 4N waves, wave tile 128x64
  const int fr = l&15, fk = l>>4;
  // staging: wave w stages rows [w*32, w*32+32); 4 lanes/row, 16B/lane.
  // global col slot = phys slot ^ ((row>>1)&3); invariant under row+16.
  const int srow = w*32 + (l>>2);
  const int sslot = l&3;
  const int swzc = (sslot ^ ((srow>>1)&3))*8;   // ushort units
  const ushort* gA0 = A + (size_t)(i0+srow)*LDK + swzc;
  const ushort* gB0 = W + (size_t)(j0+srow)*LDK + swzc;
  const int ldsOff = srow*32 + sslot*8;     // == w*1024 + l*8 : linear in lane
  auto stage = [&](int slot, int kt){
    const ushort* a = gA0 + kt*32;
    const ushort* b = gB0 + kt*32;
    __builtin_amdgcn_global_load_lds((const __attribute__((address_space(1))) void*)a,
        (__attribute__((address_space(3))) void*)(&As[slot][ldsOff]), 16, 0, 0);
    __builtin_amdgcn_global_load_lds((const __attribute__((address_space(1))) void*)(a + 16*LDK),
        (__attribute__((address_space(3))) void*)(&As[slot][ldsOff + 16*32]), 16, 0, 0);
    __builtin_amdgcn_global_load_lds((const __attribute__((address_space(1))) void*)b,
        (__attribute__((address_space(3))) void*)(&Bs[slot][ldsOff]), 16, 0, 0);
    __builtin_amdgcn_global_load_lds((const __attribute__((address_space(1))) void*)(b + 16*LDK),
        (__attribute__((address_space(3))) void*)(&Bs[slot][ldsOff + 16*32]), 16, 0, 0);
  };
  f32x4 acc[8][4] = {};
  stage(0,0); stage(1,1); stage(2,2);
  for (int t=0; t<NTI; t++){
    // tile t landed (4 loads/wave/tile; t+1,t+2 may stay in flight), collective barrier
    if (t+2 < NTI)      asm volatile("s_waitcnt vmcnt(8)\n\ts_barrier" ::: "memory");
    else if (t+1 < NTI) asm volatile("s_waitcnt vmcnt(4)\n\ts_barrier" ::: "memory");
    else                asm volatile("s_waitcnt vmcnt(0)\n\ts_barrier" ::: "memory");
    const int s = t&3;
    short8v a[8], b[4];
    #pragma unroll
    for (int m=0;m<8;m++){
      int row = wr*128 + m*16 + fr;
      a[m] = *(const short8v*)&As[s][row*32 + ((fk ^ ((row>>1)&3))*8)];
    }
    #pragma unroll
    for (int n=0;n<4;n++){
      int row = wc*64 + n*16 + fr;
      b[n] = *(const short8v*)&Bs[s][row*32 + ((fk ^ ((row>>1)&3))*8)];
    }
    // prefetch tile t+3 into slot (t+3)&3 == (t-1)&3 : its reads retired before this
    // iteration's barrier (consumed by iter t-1 MFMAs), so WAR-safe.
    if (t+3 < NTI) stage((t+3)&3, t+3);
    __builtin_amdgcn_s_setprio(1);
    #pragma unroll
    for (int m=0;m<8;m++)
      #pragma unroll
      for (int n=0;n<4;n++)
        acc[m][n] = __builtin_amdgcn_mfma_f32_16x16x32_bf16(a[m], b[n], acc[m][n], 0,0,0);
    __builtin_amdgcn_s_setprio(0);
  }
  if (MODE==2){
    float* o = (float*)outp;
    #pragma unroll
    for (int m=0;m<8;m++){
      #pragma unroll
      for (int n=0;n<4;n++){
        int col = j0 + wc*64 + n*16 + fr;
        if (col < NPH){
          int rbase = i0 + wr*128 + m*16 + fk*4;
          #pragma unroll
          for (int reg=0;reg<4;reg++)
            o[(size_t)(rbase+reg)*NPH + col] = acc[m][n][reg];
        }
      }
    }
    return;
  }
  __syncthreads();
  // epilogue: bias + max over the 16 cols (=p) of each 16x16 fragment
  const int blim = (b0+1)*NS;
  #pragma unroll
  for (int m=0;m<8;m++){
    #pragma unroll
    for (int n=0;n<4;n++){
      int colL = wc*64 + n*16 + fr;
      int rbase = wr*128 + m*16 + fk*4;
      #pragma unroll
      for (int reg=0; reg<4; reg++){
        int rowL = rbase + reg;
        float bv = (MODE==0 && (i0+rowL) >= blim) ? biasLds[1][colL] : biasLds[0][colL];
        float v = acc[m][n][reg] + bv;
        v = fmaxf(v, __shfl_xor(v,1));
        v = fmaxf(v, __shfl_xor(v,2));
        v = fmaxf(v, __shfl_xor(v,4));
        v = fmaxf(v, __shfl_xor(v,8));
        if (fr==0) outT[rowL][wc*4+n] = v;
      }
    }
  }
  __syncthreads();
  {
    int rowL = tid>>1;
    int hloc0 = (tid&1)*8;
    int hg0 = (j0>>4) + hloc0;
    if (hg0 < NH){
      int absrow = i0 + rowL;
      float v[8];
      #pragma unroll
      for (int qq=0;qq<8;qq++) v[qq] = outT[rowL][hloc0+qq];
      if (MODE==0){
        ushort* o = (ushort*)outp + (size_t)absrow*K2 + hg0;
        ushort hi[8], lo[8];
        #pragma unroll
        for (int qq=0;qq<8;qq++){ hi[qq]=f2bf(v[qq]); lo[qq]=f2bf(v[qq]-bf2f(hi[qq])); }
        *(us4*)(o)        = (us4){hi[0],hi[1],hi[2],hi[3]};
        *(us4*)(o+4)      = (us4){hi[4],hi[5],hi[6],hi[7]};
        *(us4*)(o+NH)     = (us4){lo[0],lo[1],lo[2],lo[3]};
        *(us4*)(o+NH+4)   = (us4){lo[4],lo[5],lo[6],lo[7]};
        *(us4*)(o+2*NH)   = (us4){hi[0],hi[1],hi[2],hi[3]};
        *(us4*)(o+2*NH+4) = (us4){hi[4],hi[5],hi[6],hi[7]};
      } else {
        float* o = (float*)outp + (size_t)absrow*NH + hg0;
        *(f32x4*)o     = (f32x4){v[0],v[1],v[2],v[3]};
        *(f32x4*)(o+4) = (f32x4){v[4],v[5],v[6],v[7]};
      }
    }
  }
}

// --------- hoisted m1: m1[i][h] = max_p(premod[i][h*16+p] + prer[b][h*16+p]) ---------
__global__ __launch_bounds__(256) void maxp_kernel(const float* __restrict__ premod,
    const float* __restrict__ prer, ushort* __restrict__ m1e){
  int i = blockIdx.x;
  int b = i / NS;
  int h = threadIdx.x;
  if (h >= NH) return;
  const float* pm = premod + (size_t)i*NPH + h*16;
  const float* pr = prer + (size_t)b*NPH2 + h*16;
  float v = -INFINITY;
  #pragma unroll
  for (int p=0;p<16;p+=4){
    f32x4 a = *(const f32x4*)(pm+p);
    f32x4 c = *(const f32x4*)(pr+p);
    v = fmaxf(v, fmaxf(fmaxf(a.x+c.x, a.y+c.y), fmaxf(a.z+c.z, a.w+c.w)));
  }
  ushort hi = f2bf(v), lo = f2bf(v - bf2f(hi));
  ushort* o = m1e + (size_t)i*K2;
  o[h] = hi; o[NH+h] = lo; o[2*NH+h] = hi;
}

// --------- logits main: one thread per s, grid (NB, 2) ---------
__global__ __launch_bounds__(256) void logits_main(const ushort* __restrict__ m1e,
    const float* __restrict__ m2, const float* __restrict__ W3, const float* __restrict__ b3,
    const float* __restrict__ mask, float* __restrict__ lg){
  int b=blockIdx.x;
  int s=blockIdx.y*256+threadIdx.x;
  if (s >= NS) return;
  const ushort* a = m1e + (size_t)(b*NS+s)*K2;
  const float4* d = (const float4*)(m2 + (size_t)(b*NS+s)*NH);
  float acc[NP];
  #pragma unroll
  for (int p=0;p<NP;p++) acc[p]=b3[p];
  for (int k=0;k<NH/4;k++){
    us4 hv = *(const us4*)(a + 4*k);
    us4 lv = *(const us4*)(a + NH + 4*k);
    float4 dv = d[k];
    float a0=bf2f(hv.x)+bf2f(lv.x), a1=bf2f(hv.y)+bf2f(lv.y);
    float a2=bf2f(hv.z)+bf2f(lv.z), a3=bf2f(hv.w)+bf2f(lv.w);
    #pragma unroll
    for (int p=0;p<NP;p++){
      const float* wp = W3 + p*(2*NH) + 4*k;        // wave-uniform -> s_load
      acc[p] += a0*wp[0]+a1*wp[1]+a2*wp[2]+a3*wp[3];
      const float* w2 = wp + NH;
      acc[p] += dv.x*w2[0]+dv.y*w2[1]+dv.z*w2[2]+dv.w*w2[3];
    }
  }
  float best=acc[0];
  #pragma unroll
  for (int p=1;p<NP;p++) best=fmaxf(best,acc[p]);
  lg[(size_t)b*NS+s] = (mask[(size_t)b*NS+s] > 0.f) ? best : -1e30f;
}

// --------- logits finish: log_softmax + argmax; one block per b ---------
__global__ __launch_bounds__(256) void logits_fin(const float* __restrict__ lg,
    float* __restrict__ out, int t, int* __restrict__ prevIdx){
  int b=blockIdx.x, tid=threadIdx.x;
  __shared__ float rv[256]; __shared__ int ri[256]; __shared__ float sv[256];
  float bv=-INFINITY; int bi=NS;
  for (int s=tid;s<NS;s+=256){ float v=lg[(size_t)b*NS+s]; if (v>bv){bv=v;bi=s;} }
  rv[tid]=bv; ri[tid]=bi; __syncthreads();
  for (int st=128;st>0;st>>=1){
    if (tid<st){
      float v2=rv[tid+st]; int i2=ri[tid+st];
      if (v2>rv[tid] || (v2==rv[tid] && i2<ri[tid])){ rv[tid]=v2; ri[tid]=i2; }
    }
    __syncthreads();
  }
  float mx = rv[0];
  float ps=0.f;
  for (int s=tid;s<NS;s+=256) ps += expf(lg[(size_t)b*NS+s]-mx);
  sv[tid]=ps; __syncthreads();
  for (int st=128;st>0;st>>=1){ if (tid<st) sv[tid]+=sv[tid+st]; __syncthreads(); }
  float lse = mx + logf(sv[0]);
  for (int s=tid;s<NS;s+=256) out[((size_t)b*NT + t)*NS + s] = lg[(size_t)b*NS+s]-lse;
  if (tid==0) prevIdx[b]=ri[0];
}

// =============================== host ===============================
extern "C" void kernel_launch(void* const* d_in, const int* in_sizes, int n_in,
                              void* d_out, int out_size, void* d_ws, size_t ws_size,
                              hipStream_t stream){
  const float* mod  = (const float*)d_in[1];
  const float* mask = (const float*)d_in[2];
  const float* Wih  = (const float*)d_in[3];
  const float* Whh  = (const float*)d_in[4];
  const float* bih  = (const float*)d_in[5];
  const float* bhh  = (const float*)d_in[6];
  const float* rW[2] = {(const float*)d_in[7],  (const float*)d_in[14]};
  const float* W1[2] = {(const float*)d_in[8],  (const float*)d_in[15]};
  const float* b1[2] = {(const float*)d_in[9],  (const float*)d_in[16]};
  const float* W2[2] = {(const float*)d_in[10], (const float*)d_in[17]};
  const float* b2[2] = {(const float*)d_in[11], (const float*)d_in[18]};
  const float* W3[2] = {(const float*)d_in[12], (const float*)d_in[19]};
  const float* b3[2] = {(const float*)d_in[13], (const float*)d_in[20]};
  float* out[2];
  out[0] = (float*)d_out;
  out[1] = out[0] + (size_t)NB*NT*NS;

  float* wsf = (float*)d_ws;
  size_t off = 0;
  auto carve = [&](size_t n)->size_t{ size_t o=off; off += (n + 63) & ~(size_t)63; return o; };
  float* hbuf   = wsf + carve((size_t)NB*NH);
  float* cbuf   = wsf + carve((size_t)NB*NH);
  float* prer   = wsf + carve((size_t)NB*NPH2);
  int*   sprev  = (int*)(wsf + carve(128));
  int*   eprev  = sprev + 32;
  float* m2f    = wsf + carve((size_t)NBS*NH);
  float* b2p[2] = {wsf + carve(NPH2), wsf + carve(NPH2)};
  float* b1p[2] = {wsf + carve(NPH2), wsf + carve(NPH2)};
  float* rbuf   = wsf + carve((size_t)NB*NH);
  float* gsbuf  = wsf + carve((size_t)NB*NG);
  float* lgbuf  = wsf + carve((size_t)NB*NS);
  float* W1rT[2]= {wsf + carve((size_t)NH*NPH), wsf + carve((size_t)NH*NPH)};
  ushort* modExp   = (ushort*)(wsf + carve((size_t)NBS*K1/2));
  ushort* W1exp[2] = {(ushort*)(wsf + carve((size_t)NPH2*K1/2)),
                      (ushort*)(wsf + carve((size_t)NPH2*K1/2))};
  ushort* W2exp[2] = {(ushort*)(wsf + carve((size_t)NPH2*K2/2)),
                      (ushort*)(wsf + carve((size_t)NPH2*K2/2))};
  ushort* m1exp    = (ushort*)(wsf + carve((size_t)NBS*K2/2));

  // ---- hoisted premod buffers if workspace allows (per-net fallback otherwise) ----
  const size_t premodN = (size_t)NBS * NPH;       // 40.96M floats = 163.8 MB
  size_t availF = ws_size / 4;
  int nHoist = 0;
  float* premod[2] = {nullptr, nullptr};
  if (availF >= off + 2*premodN + 128){
    nHoist = 2; premod[0] = wsf + carve(premodN); premod[1] = wsf + carve(premodN);
  } else if (availF >= off + premodN + 128){
    nHoist = 1; premod[0] = wsf + carve(premodN);
  }

  // ---- init + prep (every launch; deterministic) ----
  init_kernel<<<NB, 256, 0, stream>>>(mask, hbuf, cbuf, sprev, eprev);
  conv_mod_k<<<2048, 256, 0, stream>>>(mod, modExp);
  pad_zero_k<<<256, 256, 0, stream>>>(m1exp, K2, 3*NH, K2-3*NH, NBS);
  for (int net=0; net<2; net++){
    conv_w1_k<<<2048, 256, 0, stream>>>(W1[net], W1exp[net]);
    conv_w2_k<<<1024, 256, 0, stream>>>(W2[net], W2exp[net]);
    conv_w1r_k<<<1024, 256, 0, stream>>>(W1[net], W1rT[net]);
    permv_k<<<(NPH2+255)/256, 256, 0, stream>>>(b2[net], b2p[net]);
    permv_k<<<(NPH2+255)/256, 256, 0, stream>>>(b1[net], b1p[net]);
  }
  for (int net=0; net<nHoist; net++)
    gemm_fused<2><<<NBS/256*NJT, 512, 0, stream>>>(modExp, W1exp[net], nullptr, (void*)premod[net]);

  for (int t=0; t<NT; t++){
    lstm_gates<<<dim3(NB, NG/4), 256, 0, stream>>>(mod, sprev, eprev, hbuf,
                                                   Wih, Whh, bih, bhh, gsbuf);
    lstm_update<<<NB, 256, 0, stream>>>(gsbuf, hbuf, cbuf);
    for (int net=0; net<2; net++){
      r_kernel<<<dim3(NB, NH/4), 256, 0, stream>>>(mod, sprev, eprev, hbuf, rW[net], rbuf);
      prer_kernel<<<dim3(NB, NPH2/256), 256, 0, stream>>>(rbuf, W1rT[net], b1p[net], prer);
      if (net < nHoist)
        maxp_kernel<<<NBS, 256, 0, stream>>>(premod[net], prer, m1exp);
      else
        gemm_fused<0><<<NBS/256*NJT, 512, 0, stream>>>(modExp, W1exp[net], prer, (void*)m1exp);
      gemm_fused<1><<<NBS/256*NJT, 512, 0, stream>>>(m1exp, W2exp[net], b2p[net], (void*)m2f);
      logits_main<<<dim3(NB, 2), 256, 0, stream>>>(m1exp, m2f, W3[net], b3[net], mask, lgbuf);
      logits_fin<<<NB, 256, 0, stream>>>(lgbuf, out[net], t, net==0 ? sprev : eprev);
    }
  }
}